// Round 10
// baseline (955.980 us; speedup 1.0000x reference)
//
#include <hip/hip_runtime.h>
#include <hip/hip_bf16.h>
#include <hip/hip_fp16.h>

// GCN forward. fp16 storage for ALL inter-layer tensors incl. residual;
// fp32 accum everywhere (gather accum, MFMA accum, BN stats, readout).
// R3: MFMA GEMM, pre-swizzled W. R7: radix-bucketed CSR build.
// R8: 64-row GEMM tiles; fp16 residual; bn_fin fused into bnrelu.
// R9: column-blocked gather — 4 chunks x 32 cols, chunk-major grid. Random
//     read footprint per chunk = 6.4MB (~fits per-XCD L2) vs 25.6MB before;
//     R8 counters showed 177MB HBM/L3 fetch per gather (43% L2 miss).
//     4 lanes/node/chunk, 64B slice per edge; bit-identical accumulation.

#define N_NODES 100000
#define N_EDGES 1600000
#define N_GRAPHS 128
#define DIM 128
#define N_LAYERS 4
#define BN_EPS 1e-5f
#define NBUCK 196          // ceil(N_NODES/512)
#define EPB 6250           // edges per block in bin/scatter passes (256 blocks)
#define GBLK 1563          // gather: blocks per column chunk = ceil(100000/64)

typedef __attribute__((ext_vector_type(8))) _Float16 half8;
typedef __attribute__((ext_vector_type(4))) float floatx4;

// ---------------- pass A: bucket counts (LDS hist, 196 bins) ----------------
__global__ __launch_bounds__(256) void binA_k(const int* __restrict__ src,
                                              const int* __restrict__ dst,
                                              int* __restrict__ cnt_d,
                                              int* __restrict__ cnt_s) {
  __shared__ int hd[NBUCK], hs[NBUCK];
  int t = threadIdx.x;
  for (int i = t; i < NBUCK; i += 256) { hd[i] = 0; hs[i] = 0; }
  __syncthreads();
  int e0 = blockIdx.x * EPB;
  for (int e = e0 + t; e < e0 + EPB; e += 256) {
    atomicAdd(&hd[dst[e] >> 9], 1);
    atomicAdd(&hs[src[e] >> 9], 1);
  }
  __syncthreads();
  for (int i = t; i < NBUCK; i += 256) {
    if (hd[i]) atomicAdd(&cnt_d[i], hd[i]);
    if (hs[i]) atomicAdd(&cnt_s[i], hs[i]);
  }
}

// ---------------- scan of bucket counts -> bases + cursors ----------------
__global__ __launch_bounds__(256) void scan196_k(
    const int* __restrict__ cnt_d, const int* __restrict__ cnt_s,
    int* __restrict__ base_d, int* __restrict__ cur_d,
    int* __restrict__ base_s, int* __restrict__ cur_s,
    int* __restrict__ row_start) {
  __shared__ int sd[256], ss[256];
  int t = threadIdx.x;
  int vd = (t < NBUCK) ? cnt_d[t] : 0;
  int vs = (t < NBUCK) ? cnt_s[t] : 0;
  sd[t] = vd;
  ss[t] = vs;
  __syncthreads();
  for (int off = 1; off < 256; off <<= 1) {
    int ad = (t >= off) ? sd[t - off] : 0;
    int as = (t >= off) ? ss[t - off] : 0;
    __syncthreads();
    sd[t] += ad;
    ss[t] += as;
    __syncthreads();
  }
  if (t < NBUCK) {
    base_d[t] = sd[t] - vd;
    cur_d[t] = sd[t] - vd;
    base_s[t] = ss[t] - vs;
    cur_s[t] = ss[t] - vs;
  }
  if (t == 0) {
    base_d[NBUCK] = N_EDGES;
    base_s[NBUCK] = N_EDGES;
    row_start[N_NODES] = N_EDGES;
  }
}

// ---------------- pass B: scatter edges into bucket regions ----------------
// packed = (dst&511)<<17 | src  (src < 2^17). locs = src&511 (u16).
__global__ __launch_bounds__(256) void scat_k(
    const int* __restrict__ src, const int* __restrict__ dst,
    int* __restrict__ cur_d, int* __restrict__ cur_s,
    int* __restrict__ packed, unsigned short* __restrict__ locs) {
  __shared__ int hd[NBUCK], hs[NBUCK];
  int t = threadIdx.x;
  for (int i = t; i < NBUCK; i += 256) { hd[i] = 0; hs[i] = 0; }
  __syncthreads();
  int e0 = blockIdx.x * EPB;
  for (int e = e0 + t; e < e0 + EPB; e += 256) {
    atomicAdd(&hd[dst[e] >> 9], 1);
    atomicAdd(&hs[src[e] >> 9], 1);
  }
  __syncthreads();
  if (t < NBUCK) {  // claim chunks; hd/hs become running cursors
    hd[t] = atomicAdd(&cur_d[t], hd[t]);
    hs[t] = atomicAdd(&cur_s[t], hs[t]);
  }
  __syncthreads();
  for (int e = e0 + t; e < e0 + EPB; e += 256) {
    int s = src[e], d = dst[e];
    int slot = atomicAdd(&hd[d >> 9], 1);
    packed[slot] = ((d & 511) << 17) | s;
    int slot2 = atomicAdd(&hs[s >> 9], 1);
    locs[slot2] = (unsigned short)(s & 511);
  }
}

// ---------------- pass C (dst): per-bucket CSR: row_start + csr fill -------
__global__ __launch_bounds__(256) void cd_k(const int* __restrict__ base_d,
                                            const int* __restrict__ packed,
                                            int* __restrict__ row_start,
                                            int* __restrict__ csr_src) {
  __shared__ int sdeg[512], sinc[512], scur[512];
  int t = threadIdx.x;
  int b = blockIdx.x;
  int nbase = b << 9;
  int e0 = base_d[b], e1 = base_d[b + 1];
  sdeg[t] = 0;
  sdeg[t + 256] = 0;
  __syncthreads();
  for (int e = e0 + t; e < e1; e += 256) atomicAdd(&sdeg[packed[e] >> 17], 1);
  __syncthreads();
  sinc[t] = sdeg[t];
  sinc[t + 256] = sdeg[t + 256];
  __syncthreads();
  for (int off = 1; off < 512; off <<= 1) {
    int a0 = (t >= off) ? sinc[t - off] : 0;
    int i1 = t + 256;
    int a1 = (i1 >= off) ? sinc[i1 - off] : 0;
    __syncthreads();
    sinc[t] += a0;
    sinc[i1] += a1;
    __syncthreads();
  }
#pragma unroll
  for (int half = 0; half < 2; ++half) {
    int j = t + half * 256;
    int lofs = e0 + sinc[j] - sdeg[j];
    scur[j] = lofs;
    int node = nbase + j;
    if (node < N_NODES) row_start[node] = lofs;
  }
  __syncthreads();
  for (int e = e0 + t; e < e1; e += 256) {
    int p = packed[e];
    int slot = atomicAdd(&scur[p >> 17], 1);
    csr_src[slot] = p & 0x1FFFF;
  }
}

// ---------------- pass C (src): per-bucket histogram -> deg_out ------------
__global__ __launch_bounds__(256) void cs_k(const int* __restrict__ base_s,
                                            const unsigned short* __restrict__ locs,
                                            int* __restrict__ deg_out) {
  __shared__ int sdeg[512];
  int t = threadIdx.x;
  int b = blockIdx.x;
  int nbase = b << 9;
  int e0 = base_s[b], e1 = base_s[b + 1];
  sdeg[t] = 0;
  sdeg[t + 256] = 0;
  __syncthreads();
  for (int e = e0 + t; e < e1; e += 256) atomicAdd(&sdeg[locs[e]], 1);
  __syncthreads();
#pragma unroll
  for (int half = 0; half < 2; ++half) {
    int j = t + half * 256;
    int node = nbase + j;
    if (node < N_NODES) deg_out[node] = sdeg[j];
  }
}

// ---------------- norms (deg_in = row_start diff) ----------------
__global__ __launch_bounds__(256) void norm_k(const int* __restrict__ deg_out,
                                              const int* __restrict__ row_start,
                                              float* __restrict__ norm_src,
                                              float* __restrict__ norm_dst) {
  int i = blockIdx.x * 256 + threadIdx.x;
  if (i < N_NODES) {
    int din = row_start[i + 1] - row_start[i];
    int dso = deg_out[i] > 1 ? deg_out[i] : 1;
    int dsi = din > 1 ? din : 1;
    norm_src[i] = rsqrtf((float)dso);
    norm_dst[i] = rsqrtf((float)dsi);
  }
}

// ---------------- W pre-swizzle to B-fragment layout ----------------
__global__ __launch_bounds__(256) void wswz_k(const float* __restrict__ W,
                                              __half* __restrict__ Bsw) {
  int w = blockIdx.x >> 3, ct = blockIdx.x & 7;
  int ks = threadIdx.x >> 6, lane = threadIdx.x & 63;
  int n = ct * 16 + (lane & 15);
  int k0 = ks * 32 + (lane >> 4) * 8;
  const float* Wm = W + (size_t)w * 16384;
  __half* o = Bsw + ((((size_t)w * 8 + ct) * 4 + ks) * 64 + lane) * 8;
#pragma unroll
  for (int j = 0; j < 8; ++j) o[j] = __float2half(Wm[(k0 + j) * 128 + n]);
}

// ---------------- MFMA core: wave w computes 16 rows x 128 cols ----------
// C layout per 16x16 tile: row = quad*4 + reg, col = ct*16 + lrow.
__device__ inline void mfma_core16(const __half* sA,
                                   const __half* __restrict__ Bsw,
                                   floatx4 (&acc)[8], int w, int lane,
                                   int quad, int lrow) {
#pragma unroll
  for (int ct = 0; ct < 8; ++ct) acc[ct] = (floatx4)(0.f);
#pragma unroll
  for (int ks = 0; ks < 4; ++ks) {
    int m = w * 16 + lrow;
    half8 afrag = *(const half8*)(&sA[m * 136 + ks * 32 + quad * 8]);
#pragma unroll
    for (int ct = 0; ct < 8; ++ct) {
      half8 bfrag = *(const half8*)(&Bsw[(((size_t)ct * 4 + ks) * 64 + lane) * 8]);
      acc[ct] = __builtin_amdgcn_mfma_f32_16x16x32_f16(afrag, bfrag, acc[ct],
                                                       0, 0, 0);
    }
  }
}

// ---------------- embed GEMM: A16 = fp16(h @ W + b); P0h = fp16(.*ns) ------
__global__ __launch_bounds__(256) void mfma_gemm_f32in(
    const float* __restrict__ X32, const __half* __restrict__ Bsw,
    const float* __restrict__ bias, __half* __restrict__ A16,
    __half* __restrict__ S16, const float* __restrict__ norm_src) {
  __shared__ __half sA[64 * 136];  // 17.4 KB
  const int tid = threadIdx.x;
  const int w = tid >> 6, lane = tid & 63;
  const int quad = lane >> 4, lrow = lane & 15;
  const int row_base = blockIdx.x * 64;

  // stage fp32 tile -> fp16 LDS (2048 float4 reads)
#pragma unroll
  for (int i = 0; i < 8; ++i) {
    int g = i * 256 + tid;
    int r = g >> 5, q = g & 31;
    int row = row_base + r;
    float4 v = make_float4(0.f, 0.f, 0.f, 0.f);
    if (row < N_NODES) v = ((const float4*)X32)[(size_t)row * 32 + q];
    union { __half2 h[2]; float f[2]; } u;
    u.h[0] = __floats2half2_rn(v.x, v.y);
    u.h[1] = __floats2half2_rn(v.z, v.w);
    *(float2*)(&sA[r * 136 + q * 4]) = *(float2*)u.f;
  }
  __syncthreads();

  floatx4 acc[8];
  mfma_core16(sA, Bsw, acc, w, lane, quad, lrow);

#pragma unroll
  for (int ct = 0; ct < 8; ++ct) {
    int col = ct * 16 + lrow;
    float b = bias[col];
#pragma unroll
    for (int reg = 0; reg < 4; ++reg) {
      int row = row_base + w * 16 + quad * 4 + reg;
      if (row < N_NODES) {
        float y = acc[ct][reg] + b;
        A16[(size_t)row * 128 + col] = __float2half(y);
        S16[(size_t)row * 128 + col] = __float2half(y * norm_src[row]);
      }
    }
  }
}

// ---------------- layer GEMM: hl16 = fp16(agg16 @ W + b), + BN stats ------
__global__ __launch_bounds__(256) void mfma_gemm_f16(
    const __half* __restrict__ X16, const __half* __restrict__ Bsw,
    const float* __restrict__ bias, __half* __restrict__ hl16,
    float* __restrict__ stats) {
  __shared__ __half sA[64 * 136];
  const int tid = threadIdx.x;
  const int w = tid >> 6, lane = tid & 63;
  const int quad = lane >> 4, lrow = lane & 15;
  const int row_base = blockIdx.x * 64;

  // stage fp16 tile (1024 float4 reads)
#pragma unroll
  for (int i = 0; i < 4; ++i) {
    int g = i * 256 + tid;
    int r = g >> 4, p = g & 15;
    int row = row_base + r;
    float4 v = make_float4(0.f, 0.f, 0.f, 0.f);
    if (row < N_NODES) v = ((const float4*)X16)[(size_t)row * 16 + p];
    *(float4*)(&sA[r * 136 + p * 8]) = v;
  }
  __syncthreads();

  floatx4 acc[8];
  mfma_core16(sA, Bsw, acc, w, lane, quad, lrow);

  float psum[8], pqsum[8];
#pragma unroll
  for (int ct = 0; ct < 8; ++ct) {
    int col = ct * 16 + lrow;
    float b = bias[col];
    psum[ct] = 0.f;
    pqsum[ct] = 0.f;
#pragma unroll
    for (int reg = 0; reg < 4; ++reg) {
      int row = row_base + w * 16 + quad * 4 + reg;
      if (row < N_NODES) {
        float y = acc[ct][reg] + b;
        hl16[(size_t)row * 128 + col] = __float2half(y);
        psum[ct] += y;
        pqsum[ct] += y * y;
      }
    }
  }

#pragma unroll
  for (int ct = 0; ct < 8; ++ct) {
    psum[ct] += __shfl_xor(psum[ct], 16, 64);
    psum[ct] += __shfl_xor(psum[ct], 32, 64);
    pqsum[ct] += __shfl_xor(pqsum[ct], 16, 64);
    pqsum[ct] += __shfl_xor(pqsum[ct], 32, 64);
  }
  __syncthreads();
  float* sred = (float*)sA;  // [4 waves][128] sum | [4][128] sumsq
  if (quad == 0) {
#pragma unroll
    for (int ct = 0; ct < 8; ++ct) {
      sred[w * 128 + ct * 16 + lrow] = psum[ct];
      sred[512 + w * 128 + ct * 16 + lrow] = pqsum[ct];
    }
  }
  __syncthreads();
  if (tid < 128) {
    float s = sred[tid] + sred[128 + tid] + sred[256 + tid] + sred[384 + tid];
    float q = sred[512 + tid] + sred[640 + tid] + sred[768 + tid] +
              sred[896 + tid];
    atomicAdd(&stats[tid], s);
    atomicAdd(&stats[128 + tid], q);
  }
}

// ---------------- BN apply + ReLU + residual (bn_fin fused) ----------------
__global__ __launch_bounds__(256) void bnrelu_k(
    const __half* __restrict__ hl16, __half* __restrict__ A16,
    __half* __restrict__ S, const float* __restrict__ stats,
    const float* __restrict__ gamma, const float* __restrict__ beta,
    const float* __restrict__ norm_src, int write_scaled) {
  __shared__ float ssc[128], ssh[128];
  int t = threadIdx.x;
  if (t < 128) {
    const float invn = 1.0f / (float)N_NODES;
    float mean = stats[t] * invn;
    float var = stats[128 + t] * invn - mean * mean;
    var = fmaxf(var, 0.f);
    float sc = gamma[t] * rsqrtf(var + BN_EPS);
    ssc[t] = sc;
    ssh[t] = beta[t] - mean * sc;
  }
  __syncthreads();
  int idx = blockIdx.x * 256 + t;  // < N_NODES*16
  int node = idx >> 4;
  int c0 = (idx & 15) * 8;
  float4 hv4 = *(const float4*)(hl16 + (size_t)idx * 8);
  float4 av4 = *(const float4*)(A16 + (size_t)idx * 8);
  const __half2* hp = (const __half2*)&hv4;
  const __half2* ap = (const __half2*)&av4;
  float n = write_scaled ? norm_src[node] : 0.f;
  float v[8];
#pragma unroll
  for (int q = 0; q < 4; ++q) {
    float2 f = __half22float2(hp[q]);
    float2 a = __half22float2(ap[q]);
    v[2 * q] = fmaxf(f.x * ssc[c0 + 2 * q] + ssh[c0 + 2 * q], 0.f) + a.x;
    v[2 * q + 1] =
        fmaxf(f.y * ssc[c0 + 2 * q + 1] + ssh[c0 + 2 * q + 1], 0.f) + a.y;
  }
  union { __half2 h[4]; float4 f; } ua;
#pragma unroll
  for (int q = 0; q < 4; ++q)
    ua.h[q] = __floats2half2_rn(v[2 * q], v[2 * q + 1]);
  *(float4*)(A16 + (size_t)idx * 8) = ua.f;
  if (write_scaled) {
    union { __half2 h[4]; float4 f; } us;
#pragma unroll
    for (int q = 0; q < 4; ++q)
      us.h[q] = __floats2half2_rn(v[2 * q] * n, v[2 * q + 1] * n);
    *(float4*)(S + (size_t)idx * 8) = us.f;
  }
}

// ---------------- column-blocked pull aggregation ----------------
// Grid = 4 chunks x GBLK blocks, chunk-major (chunk c's blocks dispatch
// together -> live random-read footprint ~6.4MB, near per-XCD L2 size).
// 4 lanes per node; lane owns one float4 (8 halves) of the 32-col chunk.
// fp32 accum; accumulation order per column identical to R8 (bit-exact).
__device__ inline void acc8(float (&a)[8], float4 v) {
  const __half2* hp = (const __half2*)&v;
#pragma unroll
  for (int q = 0; q < 4; ++q) {
    float2 f = __half22float2(hp[q]);
    a[2 * q] += f.x;
    a[2 * q + 1] += f.y;
  }
}

__global__ __launch_bounds__(256) void gather_k(
    const float4* __restrict__ Hs, const int* __restrict__ row_start,
    const int* __restrict__ csr_src, const float* __restrict__ norm_dst,
    float4* __restrict__ out) {
  int c = blockIdx.x / GBLK;            // column chunk 0..3
  int nb = blockIdx.x - c * GBLK;
  int node = nb * 64 + (threadIdx.x >> 2);
  int lane = threadIdx.x & 3;
  if (node >= N_NODES) return;
  int col4 = c * 4 + lane;              // float4 slot within the 16-slot row
  int s0 = row_start[node], s1 = row_start[node + 1];
  float a[8] = {0.f, 0.f, 0.f, 0.f, 0.f, 0.f, 0.f, 0.f};
  for (int e = s0; e < s1; e += 8) {
    int rem = s1 - e;
    int cnt = rem < 8 ? rem : 8;
    int ia = (lane < cnt) ? csr_src[e + lane] : 0;
    int ib = (lane + 4 < cnt) ? csr_src[e + lane + 4] : 0;
    if (cnt == 8) {
      int j0 = __shfl(ia, 0, 4), j1 = __shfl(ia, 1, 4);
      int j2 = __shfl(ia, 2, 4), j3 = __shfl(ia, 3, 4);
      int j4 = __shfl(ib, 0, 4), j5 = __shfl(ib, 1, 4);
      int j6 = __shfl(ib, 2, 4), j7 = __shfl(ib, 3, 4);
      float4 v0 = Hs[(size_t)j0 * 16 + col4];
      float4 v1 = Hs[(size_t)j1 * 16 + col4];
      float4 v2 = Hs[(size_t)j2 * 16 + col4];
      float4 v3 = Hs[(size_t)j3 * 16 + col4];
      float4 v4 = Hs[(size_t)j4 * 16 + col4];
      float4 v5 = Hs[(size_t)j5 * 16 + col4];
      float4 v6 = Hs[(size_t)j6 * 16 + col4];
      float4 v7 = Hs[(size_t)j7 * 16 + col4];
      acc8(a, v0); acc8(a, v1); acc8(a, v2); acc8(a, v3);
      acc8(a, v4); acc8(a, v5); acc8(a, v6); acc8(a, v7);
    } else {
      for (int j = 0; j < cnt; ++j) {
        int s = __shfl(j < 4 ? ia : ib, j & 3, 4);
        acc8(a, Hs[(size_t)s * 16 + col4]);
      }
    }
  }
  float nd = norm_dst[node];
  union { __half2 h[4]; float4 f; } u;
  u.h[0] = __floats2half2_rn(a[0] * nd, a[1] * nd);
  u.h[1] = __floats2half2_rn(a[2] * nd, a[3] * nd);
  u.h[2] = __floats2half2_rn(a[4] * nd, a[5] * nd);
  u.h[3] = __floats2half2_rn(a[6] * nd, a[7] * nd);
  out[(size_t)node * 16 + col4] = u.f;
}

// ---------------- readout ----------------
__global__ __launch_bounds__(256) void gbounds_k(const int* __restrict__ gid,
                                                 int* __restrict__ gstart) {
  int g = threadIdx.x;  // 0..128
  if (g > N_GRAPHS) return;
  int lo = 0, hi = N_NODES;
  while (lo < hi) {
    int mid = (lo + hi) >> 1;
    if (gid[mid] < g) lo = mid + 1; else hi = mid;
  }
  gstart[g] = lo;
}

__global__ __launch_bounds__(128) void gsum_k(const __half* __restrict__ A16,
                                              const int* __restrict__ gid,
                                              float* gsum) {
  int c = threadIdx.x;
  int n0 = blockIdx.x * 128;
  int n1 = n0 + 128;
  if (n1 > N_NODES) n1 = N_NODES;
  int cur = gid[n0];
  float local = 0.f;
  for (int n = n0; n < n1; ++n) {
    int g = gid[n];  // sorted: few changes per block
    if (g != cur) {
      atomicAdd(&gsum[cur * 128 + c], local);
      local = 0.f;
      cur = g;
    }
    local += __half2float(A16[(size_t)n * 128 + c]);
  }
  atomicAdd(&gsum[cur * 128 + c], local);
}

__global__ __launch_bounds__(128) void gout_k(const float* __restrict__ gsum,
                                              const int* __restrict__ gstart,
                                              float* __restrict__ out) {
  int g = blockIdx.x, c = threadIdx.x;
  float cnt = (float)(gstart[g + 1] - gstart[g]);
  if (cnt < 1.f) cnt = 1.f;
  out[g * 128 + c] = gsum[g * 128 + c] / cnt;
}

// ---------------- launch ----------------
extern "C" void kernel_launch(void* const* d_in, const int* in_sizes, int n_in,
                              void* d_out, int out_size, void* d_ws,
                              size_t ws_size, hipStream_t stream) {
  const float* h = (const float*)d_in[0];
  const int* src = (const int*)d_in[1];
  const int* dst = (const int*)d_in[2];
  const int* gid = (const int*)d_in[3];
  const float* W_embed = (const float*)d_in[4];
  const float* b_embed = (const float*)d_in[5];
  const float* W_layers = (const float*)d_in[6];
  const float* b_layers = (const float*)d_in[7];
  const float* gamma = (const float*)d_in[8];
  const float* beta = (const float*)d_in[9];
  float* out = (float*)d_out;
  (void)in_sizes; (void)n_in; (void)out_size; (void)ws_size;

  char* ws = (char*)d_ws;
  size_t o = 0;
  auto alloc = [&](size_t bytes) -> char* {
    char* p = ws + o;
    o = (o + bytes + 255) & ~(size_t)255;
    return p;
  };
  int* cnt_d = (int*)alloc(NBUCK * 4);  // zeroed (one memset w/ cnt_s)
  int* cnt_s = (int*)alloc(NBUCK * 4);
  int* base_d = (int*)alloc((NBUCK + 1) * 4);
  int* cur_d = (int*)alloc(NBUCK * 4);
  int* base_s = (int*)alloc((NBUCK + 1) * 4);
  int* cur_s = (int*)alloc(NBUCK * 4);
  float* norm_src = (float*)alloc(N_NODES * 4);
  float* norm_dst = (float*)alloc(N_NODES * 4);
  int* deg_out = (int*)alloc(N_NODES * 4);
  int* row_start = (int*)alloc((N_NODES + 1) * 4);
  int* csr_src = (int*)alloc((size_t)N_EDGES * 4);
  int* packed = (int*)alloc((size_t)N_EDGES * 4);
  unsigned short* locs = (unsigned short*)alloc((size_t)N_EDGES * 2);
  float* stats4 = (float*)alloc(N_LAYERS * 256 * 4);  // per-layer sum|sumsq
  float* gsum = (float*)alloc(N_GRAPHS * 128 * 4);    // adjacent to stats4
  int* gstart = (int*)alloc((N_GRAPHS + 1) * 4);
  __half* Bsw = (__half*)alloc(5 * 16384 * 2);
  __half* A16 = (__half*)alloc((size_t)N_NODES * 128 * 2);  // residual (fp16)
  __half* P0h = (__half*)alloc((size_t)N_NODES * 128 * 2);  // h*ns (fp16)
  __half* P1h = (__half*)alloc((size_t)N_NODES * 128 * 2);  // agg (fp16)
  __half* H16 = (__half*)alloc((size_t)N_NODES * 128 * 2);  // hl (fp16)

  // zero bucket counters and stats (+gsum, contiguous)
  hipMemsetAsync(cnt_d, 0, 2048, stream);
  hipMemsetAsync(stats4, 0, 4096 + 65536, stream);

  // ---- radix CSR build ----
  binA_k<<<256, 256, 0, stream>>>(src, dst, cnt_d, cnt_s);
  scan196_k<<<1, 256, 0, stream>>>(cnt_d, cnt_s, base_d, cur_d, base_s, cur_s,
                                   row_start);
  scat_k<<<256, 256, 0, stream>>>(src, dst, cur_d, cur_s, packed, locs);
  cd_k<<<NBUCK, 256, 0, stream>>>(base_d, packed, row_start, csr_src);
  cs_k<<<NBUCK, 256, 0, stream>>>(base_s, locs, deg_out);
  norm_k<<<(N_NODES + 255) / 256, 256, 0, stream>>>(deg_out, row_start,
                                                    norm_src, norm_dst);

  wswz_k<<<8, 256, 0, stream>>>(W_embed, Bsw);
  wswz_k<<<32, 256, 0, stream>>>(W_layers, Bsw + 16384);

  // embed: A16 = fp16(h @ W_embed + b) ; P0h = fp16(. * norm_src)
  mfma_gemm_f32in<<<(N_NODES + 63) / 64, 256, 0, stream>>>(
      h, Bsw, b_embed, A16, P0h, norm_src);

  for (int l = 0; l < N_LAYERS; ++l) {
    gather_k<<<4 * GBLK, 256, 0, stream>>>(
        (const float4*)P0h, row_start, csr_src, norm_dst, (float4*)P1h);
    mfma_gemm_f16<<<(N_NODES + 63) / 64, 256, 0, stream>>>(
        P1h, Bsw + (size_t)(1 + l) * 16384, b_layers + l * DIM, H16,
        stats4 + l * 256);
    bnrelu_k<<<(N_NODES * 16 + 255) / 256, 256, 0, stream>>>(
        H16, A16, P0h, stats4 + l * 256, gamma + l * DIM, beta + l * DIM,
        norm_src, (l < N_LAYERS - 1) ? 1 : 0);
  }

  gbounds_k<<<1, 256, 0, stream>>>(gid, gstart);
  gsum_k<<<(N_NODES + 127) / 128, 128, 0, stream>>>(A16, gid, gsum);
  gout_k<<<N_GRAPHS, 128, 0, stream>>>(gsum, gstart, out);
}

// Round 11
// 682.444 us; speedup vs baseline: 1.4008x; 1.4008x over previous
//
#include <hip/hip_runtime.h>
#include <hip/hip_bf16.h>
#include <hip/hip_fp16.h>

// GCN forward. fp16 inter-layer tensors; gather operand fp8 e4m3 (one
// 128B cache line per row); fp32 accum everywhere.
// R3: MFMA GEMM, pre-swizzled W. R7: radix-bucketed CSR build.
// R8: 64-row GEMM tiles; fp16 residual; bn_fin fused into bnrelu.
// R9 (REVERTED): column-blocked gather — sliced rows below the 128B line,
//     doubling line fetches (FETCH 177->326MB). Lesson: never split a
//     randomly-accessed row across temporally-separated passes.
// R10: gather operand fp8 e4m3 — row = 128B = exactly one L2 line per edge
//     (was 256B = 2 lines); footprint 25.6->12.8MB; logical traffic halves.
//     HW cvt (v_cvt_pk_f32_fp8 / v_cvt_pk_fp8_f32). Only the gather operand
//     is fp8; accumulation/GEMM/BN/residual unchanged.

#define N_NODES 100000
#define N_EDGES 1600000
#define N_GRAPHS 128
#define DIM 128
#define N_LAYERS 4
#define BN_EPS 1e-5f
#define NBUCK 196          // ceil(N_NODES/512)
#define EPB 6250           // edges per block in bin/scatter passes (256 blocks)

typedef __attribute__((ext_vector_type(8))) _Float16 half8;
typedef __attribute__((ext_vector_type(4))) float floatx4;
typedef __attribute__((ext_vector_type(2))) float floatx2;

// ---------------- pass A: bucket counts (LDS hist, 196 bins) ----------------
__global__ __launch_bounds__(256) void binA_k(const int* __restrict__ src,
                                              const int* __restrict__ dst,
                                              int* __restrict__ cnt_d,
                                              int* __restrict__ cnt_s) {
  __shared__ int hd[NBUCK], hs[NBUCK];
  int t = threadIdx.x;
  for (int i = t; i < NBUCK; i += 256) { hd[i] = 0; hs[i] = 0; }
  __syncthreads();
  int e0 = blockIdx.x * EPB;
  for (int e = e0 + t; e < e0 + EPB; e += 256) {
    atomicAdd(&hd[dst[e] >> 9], 1);
    atomicAdd(&hs[src[e] >> 9], 1);
  }
  __syncthreads();
  for (int i = t; i < NBUCK; i += 256) {
    if (hd[i]) atomicAdd(&cnt_d[i], hd[i]);
    if (hs[i]) atomicAdd(&cnt_s[i], hs[i]);
  }
}

// ---------------- scan of bucket counts -> bases + cursors ----------------
__global__ __launch_bounds__(256) void scan196_k(
    const int* __restrict__ cnt_d, const int* __restrict__ cnt_s,
    int* __restrict__ base_d, int* __restrict__ cur_d,
    int* __restrict__ base_s, int* __restrict__ cur_s,
    int* __restrict__ row_start) {
  __shared__ int sd[256], ss[256];
  int t = threadIdx.x;
  int vd = (t < NBUCK) ? cnt_d[t] : 0;
  int vs = (t < NBUCK) ? cnt_s[t] : 0;
  sd[t] = vd;
  ss[t] = vs;
  __syncthreads();
  for (int off = 1; off < 256; off <<= 1) {
    int ad = (t >= off) ? sd[t - off] : 0;
    int as = (t >= off) ? ss[t - off] : 0;
    __syncthreads();
    sd[t] += ad;
    ss[t] += as;
    __syncthreads();
  }
  if (t < NBUCK) {
    base_d[t] = sd[t] - vd;
    cur_d[t] = sd[t] - vd;
    base_s[t] = ss[t] - vs;
    cur_s[t] = ss[t] - vs;
  }
  if (t == 0) {
    base_d[NBUCK] = N_EDGES;
    base_s[NBUCK] = N_EDGES;
    row_start[N_NODES] = N_EDGES;
  }
}

// ---------------- pass B: scatter edges into bucket regions ----------------
// packed = (dst&511)<<17 | src  (src < 2^17). locs = src&511 (u16).
__global__ __launch_bounds__(256) void scat_k(
    const int* __restrict__ src, const int* __restrict__ dst,
    int* __restrict__ cur_d, int* __restrict__ cur_s,
    int* __restrict__ packed, unsigned short* __restrict__ locs) {
  __shared__ int hd[NBUCK], hs[NBUCK];
  int t = threadIdx.x;
  for (int i = t; i < NBUCK; i += 256) { hd[i] = 0; hs[i] = 0; }
  __syncthreads();
  int e0 = blockIdx.x * EPB;
  for (int e = e0 + t; e < e0 + EPB; e += 256) {
    atomicAdd(&hd[dst[e] >> 9], 1);
    atomicAdd(&hs[src[e] >> 9], 1);
  }
  __syncthreads();
  if (t < NBUCK) {  // claim chunks; hd/hs become running cursors
    hd[t] = atomicAdd(&cur_d[t], hd[t]);
    hs[t] = atomicAdd(&cur_s[t], hs[t]);
  }
  __syncthreads();
  for (int e = e0 + t; e < e0 + EPB; e += 256) {
    int s = src[e], d = dst[e];
    int slot = atomicAdd(&hd[d >> 9], 1);
    packed[slot] = ((d & 511) << 17) | s;
    int slot2 = atomicAdd(&hs[s >> 9], 1);
    locs[slot2] = (unsigned short)(s & 511);
  }
}

// ---------------- pass C (dst): per-bucket CSR: row_start + csr fill -------
__global__ __launch_bounds__(256) void cd_k(const int* __restrict__ base_d,
                                            const int* __restrict__ packed,
                                            int* __restrict__ row_start,
                                            int* __restrict__ csr_src) {
  __shared__ int sdeg[512], sinc[512], scur[512];
  int t = threadIdx.x;
  int b = blockIdx.x;
  int nbase = b << 9;
  int e0 = base_d[b], e1 = base_d[b + 1];
  sdeg[t] = 0;
  sdeg[t + 256] = 0;
  __syncthreads();
  for (int e = e0 + t; e < e1; e += 256) atomicAdd(&sdeg[packed[e] >> 17], 1);
  __syncthreads();
  sinc[t] = sdeg[t];
  sinc[t + 256] = sdeg[t + 256];
  __syncthreads();
  for (int off = 1; off < 512; off <<= 1) {
    int a0 = (t >= off) ? sinc[t - off] : 0;
    int i1 = t + 256;
    int a1 = (i1 >= off) ? sinc[i1 - off] : 0;
    __syncthreads();
    sinc[t] += a0;
    sinc[i1] += a1;
    __syncthreads();
  }
#pragma unroll
  for (int half = 0; half < 2; ++half) {
    int j = t + half * 256;
    int lofs = e0 + sinc[j] - sdeg[j];
    scur[j] = lofs;
    int node = nbase + j;
    if (node < N_NODES) row_start[node] = lofs;
  }
  __syncthreads();
  for (int e = e0 + t; e < e1; e += 256) {
    int p = packed[e];
    int slot = atomicAdd(&scur[p >> 17], 1);
    csr_src[slot] = p & 0x1FFFF;
  }
}

// ---------------- pass C (src): per-bucket histogram -> deg_out ------------
__global__ __launch_bounds__(256) void cs_k(const int* __restrict__ base_s,
                                            const unsigned short* __restrict__ locs,
                                            int* __restrict__ deg_out) {
  __shared__ int sdeg[512];
  int t = threadIdx.x;
  int b = blockIdx.x;
  int nbase = b << 9;
  int e0 = base_s[b], e1 = base_s[b + 1];
  sdeg[t] = 0;
  sdeg[t + 256] = 0;
  __syncthreads();
  for (int e = e0 + t; e < e1; e += 256) atomicAdd(&sdeg[locs[e]], 1);
  __syncthreads();
#pragma unroll
  for (int half = 0; half < 2; ++half) {
    int j = t + half * 256;
    int node = nbase + j;
    if (node < N_NODES) deg_out[node] = sdeg[j];
  }
}

// ---------------- norms (deg_in = row_start diff) ----------------
__global__ __launch_bounds__(256) void norm_k(const int* __restrict__ deg_out,
                                              const int* __restrict__ row_start,
                                              float* __restrict__ norm_src,
                                              float* __restrict__ norm_dst) {
  int i = blockIdx.x * 256 + threadIdx.x;
  if (i < N_NODES) {
    int din = row_start[i + 1] - row_start[i];
    int dso = deg_out[i] > 1 ? deg_out[i] : 1;
    int dsi = din > 1 ? din : 1;
    norm_src[i] = rsqrtf((float)dso);
    norm_dst[i] = rsqrtf((float)dsi);
  }
}

// ---------------- W pre-swizzle to B-fragment layout ----------------
__global__ __launch_bounds__(256) void wswz_k(const float* __restrict__ W,
                                              __half* __restrict__ Bsw) {
  int w = blockIdx.x >> 3, ct = blockIdx.x & 7;
  int ks = threadIdx.x >> 6, lane = threadIdx.x & 63;
  int n = ct * 16 + (lane & 15);
  int k0 = ks * 32 + (lane >> 4) * 8;
  const float* Wm = W + (size_t)w * 16384;
  __half* o = Bsw + ((((size_t)w * 8 + ct) * 4 + ks) * 64 + lane) * 8;
#pragma unroll
  for (int j = 0; j < 8; ++j) o[j] = __float2half(Wm[(k0 + j) * 128 + n]);
}

// ---------------- MFMA core: wave w computes 16 rows x 128 cols ----------
// C layout per 16x16 tile: row = quad*4 + reg, col = ct*16 + lrow.
__device__ inline void mfma_core16(const __half* sA,
                                   const __half* __restrict__ Bsw,
                                   floatx4 (&acc)[8], int w, int lane,
                                   int quad, int lrow) {
#pragma unroll
  for (int ct = 0; ct < 8; ++ct) acc[ct] = (floatx4)(0.f);
#pragma unroll
  for (int ks = 0; ks < 4; ++ks) {
    int m = w * 16 + lrow;
    half8 afrag = *(const half8*)(&sA[m * 136 + ks * 32 + quad * 8]);
#pragma unroll
    for (int ct = 0; ct < 8; ++ct) {
      half8 bfrag = *(const half8*)(&Bsw[(((size_t)ct * 4 + ks) * 64 + lane) * 8]);
      acc[ct] = __builtin_amdgcn_mfma_f32_16x16x32_f16(afrag, bfrag, acc[ct],
                                                       0, 0, 0);
    }
  }
}

// ---------------- embed GEMM: A16 = fp16(h @ W + b); P0f8 = fp8(.*ns) ------
__global__ __launch_bounds__(256) void mfma_gemm_f32in(
    const float* __restrict__ X32, const __half* __restrict__ Bsw,
    const float* __restrict__ bias, __half* __restrict__ A16,
    unsigned char* __restrict__ S8, const float* __restrict__ norm_src) {
  __shared__ __half sA[64 * 136];  // 17.4 KB
  const int tid = threadIdx.x;
  const int w = tid >> 6, lane = tid & 63;
  const int quad = lane >> 4, lrow = lane & 15;
  const int row_base = blockIdx.x * 64;

  // stage fp32 tile -> fp16 LDS (2048 float4 reads)
#pragma unroll
  for (int i = 0; i < 8; ++i) {
    int g = i * 256 + tid;
    int r = g >> 5, q = g & 31;
    int row = row_base + r;
    float4 v = make_float4(0.f, 0.f, 0.f, 0.f);
    if (row < N_NODES) v = ((const float4*)X32)[(size_t)row * 32 + q];
    union { __half2 h[2]; float f[2]; } u;
    u.h[0] = __floats2half2_rn(v.x, v.y);
    u.h[1] = __floats2half2_rn(v.z, v.w);
    *(float2*)(&sA[r * 136 + q * 4]) = *(float2*)u.f;
  }
  __syncthreads();

  floatx4 acc[8];
  mfma_core16(sA, Bsw, acc, w, lane, quad, lrow);

#pragma unroll
  for (int ct = 0; ct < 8; ++ct) {
    int col = ct * 16 + lrow;
    float b = bias[col];
#pragma unroll
    for (int reg = 0; reg < 4; ++reg) {
      int row = row_base + w * 16 + quad * 4 + reg;
      if (row < N_NODES) {
        float y = acc[ct][reg] + b;
        A16[(size_t)row * 128 + col] = __float2half(y);
        unsigned pb =
            __builtin_amdgcn_cvt_pk_fp8_f32(y * norm_src[row], 0.f, 0, false);
        S8[(size_t)row * 128 + col] = (unsigned char)(pb & 0xFF);
      }
    }
  }
}

// ---------------- layer GEMM: hl16 = fp16(agg16 @ W + b), + BN stats ------
__global__ __launch_bounds__(256) void mfma_gemm_f16(
    const __half* __restrict__ X16, const __half* __restrict__ Bsw,
    const float* __restrict__ bias, __half* __restrict__ hl16,
    float* __restrict__ stats) {
  __shared__ __half sA[64 * 136];
  const int tid = threadIdx.x;
  const int w = tid >> 6, lane = tid & 63;
  const int quad = lane >> 4, lrow = lane & 15;
  const int row_base = blockIdx.x * 64;

  // stage fp16 tile (1024 float4 reads)
#pragma unroll
  for (int i = 0; i < 4; ++i) {
    int g = i * 256 + tid;
    int r = g >> 4, p = g & 15;
    int row = row_base + r;
    float4 v = make_float4(0.f, 0.f, 0.f, 0.f);
    if (row < N_NODES) v = ((const float4*)X16)[(size_t)row * 16 + p];
    *(float4*)(&sA[r * 136 + p * 8]) = v;
  }
  __syncthreads();

  floatx4 acc[8];
  mfma_core16(sA, Bsw, acc, w, lane, quad, lrow);

  float psum[8], pqsum[8];
#pragma unroll
  for (int ct = 0; ct < 8; ++ct) {
    int col = ct * 16 + lrow;
    float b = bias[col];
    psum[ct] = 0.f;
    pqsum[ct] = 0.f;
#pragma unroll
    for (int reg = 0; reg < 4; ++reg) {
      int row = row_base + w * 16 + quad * 4 + reg;
      if (row < N_NODES) {
        float y = acc[ct][reg] + b;
        hl16[(size_t)row * 128 + col] = __float2half(y);
        psum[ct] += y;
        pqsum[ct] += y * y;
      }
    }
  }

#pragma unroll
  for (int ct = 0; ct < 8; ++ct) {
    psum[ct] += __shfl_xor(psum[ct], 16, 64);
    psum[ct] += __shfl_xor(psum[ct], 32, 64);
    pqsum[ct] += __shfl_xor(pqsum[ct], 16, 64);
    pqsum[ct] += __shfl_xor(pqsum[ct], 32, 64);
  }
  __syncthreads();
  float* sred = (float*)sA;  // [4 waves][128] sum | [4][128] sumsq
  if (quad == 0) {
#pragma unroll
    for (int ct = 0; ct < 8; ++ct) {
      sred[w * 128 + ct * 16 + lrow] = psum[ct];
      sred[512 + w * 128 + ct * 16 + lrow] = pqsum[ct];
    }
  }
  __syncthreads();
  if (tid < 128) {
    float s = sred[tid] + sred[128 + tid] + sred[256 + tid] + sred[384 + tid];
    float q = sred[512 + tid] + sred[640 + tid] + sred[768 + tid] +
              sred[896 + tid];
    atomicAdd(&stats[tid], s);
    atomicAdd(&stats[128 + tid], q);
  }
}

// ---------------- BN apply + ReLU + residual (bn_fin fused) ----------------
// Writes fp8 scaled copy (gather operand) when write_scaled.
__global__ __launch_bounds__(256) void bnrelu_k(
    const __half* __restrict__ hl16, __half* __restrict__ A16,
    unsigned char* __restrict__ S8, const float* __restrict__ stats,
    const float* __restrict__ gamma, const float* __restrict__ beta,
    const float* __restrict__ norm_src, int write_scaled) {
  __shared__ float ssc[128], ssh[128];
  int t = threadIdx.x;
  if (t < 128) {
    const float invn = 1.0f / (float)N_NODES;
    float mean = stats[t] * invn;
    float var = stats[128 + t] * invn - mean * mean;
    var = fmaxf(var, 0.f);
    float sc = gamma[t] * rsqrtf(var + BN_EPS);
    ssc[t] = sc;
    ssh[t] = beta[t] - mean * sc;
  }
  __syncthreads();
  int idx = blockIdx.x * 256 + t;  // < N_NODES*16
  int node = idx >> 4;
  int c0 = (idx & 15) * 8;
  float4 hv4 = *(const float4*)(hl16 + (size_t)idx * 8);
  float4 av4 = *(const float4*)(A16 + (size_t)idx * 8);
  const __half2* hp = (const __half2*)&hv4;
  const __half2* ap = (const __half2*)&av4;
  float n = write_scaled ? norm_src[node] : 0.f;
  float v[8];
#pragma unroll
  for (int q = 0; q < 4; ++q) {
    float2 f = __half22float2(hp[q]);
    float2 a = __half22float2(ap[q]);
    v[2 * q] = fmaxf(f.x * ssc[c0 + 2 * q] + ssh[c0 + 2 * q], 0.f) + a.x;
    v[2 * q + 1] =
        fmaxf(f.y * ssc[c0 + 2 * q + 1] + ssh[c0 + 2 * q + 1], 0.f) + a.y;
  }
  union { __half2 h[4]; float4 f; } ua;
#pragma unroll
  for (int q = 0; q < 4; ++q)
    ua.h[q] = __floats2half2_rn(v[2 * q], v[2 * q + 1]);
  *(float4*)(A16 + (size_t)idx * 8) = ua.f;
  if (write_scaled) {
    unsigned lo = 0, hi = 0;
    lo = __builtin_amdgcn_cvt_pk_fp8_f32(v[0] * n, v[1] * n, lo, false);
    lo = __builtin_amdgcn_cvt_pk_fp8_f32(v[2] * n, v[3] * n, lo, true);
    hi = __builtin_amdgcn_cvt_pk_fp8_f32(v[4] * n, v[5] * n, hi, false);
    hi = __builtin_amdgcn_cvt_pk_fp8_f32(v[6] * n, v[7] * n, hi, true);
    ((uint2*)S8)[idx] = make_uint2(lo, hi);
  }
}

// ---------------- pull aggregation (fp8 in, fp16 out, fp32 accum) ---------
// 16 lanes/node, lane owns 8 fp8 cols (8B); one 128B line per edge.
__device__ inline void accf8(float (&a)[8], uint2 v) {
  floatx2 f;
  f = __builtin_amdgcn_cvt_pk_f32_fp8(v.x, false); a[0] += f.x; a[1] += f.y;
  f = __builtin_amdgcn_cvt_pk_f32_fp8(v.x, true);  a[2] += f.x; a[3] += f.y;
  f = __builtin_amdgcn_cvt_pk_f32_fp8(v.y, false); a[4] += f.x; a[5] += f.y;
  f = __builtin_amdgcn_cvt_pk_f32_fp8(v.y, true);  a[6] += f.x; a[7] += f.y;
}

__global__ __launch_bounds__(256) void gather_k(
    const uint2* __restrict__ Hs, const int* __restrict__ row_start,
    const int* __restrict__ csr_src, const float* __restrict__ norm_dst,
    __half* __restrict__ out) {
  int node = (blockIdx.x * 256 + threadIdx.x) >> 4;
  int lane = threadIdx.x & 15;
  if (node >= N_NODES) return;
  int s0 = row_start[node], s1 = row_start[node + 1];
  float a[8] = {0.f, 0.f, 0.f, 0.f, 0.f, 0.f, 0.f, 0.f};
  for (int e = s0; e < s1; e += 16) {
    int cnt = s1 - e;
    if (cnt > 16) cnt = 16;
    int idx = (lane < cnt) ? csr_src[e + lane] : 0;
    int j = 0;
    for (; j + 8 <= cnt; j += 8) {
      uint2 v0 = Hs[(size_t)__shfl(idx, j, 16) * 16 + lane];
      uint2 v1 = Hs[(size_t)__shfl(idx, j + 1, 16) * 16 + lane];
      uint2 v2 = Hs[(size_t)__shfl(idx, j + 2, 16) * 16 + lane];
      uint2 v3 = Hs[(size_t)__shfl(idx, j + 3, 16) * 16 + lane];
      uint2 v4 = Hs[(size_t)__shfl(idx, j + 4, 16) * 16 + lane];
      uint2 v5 = Hs[(size_t)__shfl(idx, j + 5, 16) * 16 + lane];
      uint2 v6 = Hs[(size_t)__shfl(idx, j + 6, 16) * 16 + lane];
      uint2 v7 = Hs[(size_t)__shfl(idx, j + 7, 16) * 16 + lane];
      accf8(a, v0); accf8(a, v1); accf8(a, v2); accf8(a, v3);
      accf8(a, v4); accf8(a, v5); accf8(a, v6); accf8(a, v7);
    }
    for (; j + 4 <= cnt; j += 4) {
      uint2 v0 = Hs[(size_t)__shfl(idx, j, 16) * 16 + lane];
      uint2 v1 = Hs[(size_t)__shfl(idx, j + 1, 16) * 16 + lane];
      uint2 v2 = Hs[(size_t)__shfl(idx, j + 2, 16) * 16 + lane];
      uint2 v3 = Hs[(size_t)__shfl(idx, j + 3, 16) * 16 + lane];
      accf8(a, v0); accf8(a, v1); accf8(a, v2); accf8(a, v3);
    }
    for (; j < cnt; ++j) {
      accf8(a, Hs[(size_t)__shfl(idx, j, 16) * 16 + lane]);
    }
  }
  float nd = norm_dst[node];
  union { __half2 h[4]; float4 f; } u;
  u.h[0] = __floats2half2_rn(a[0] * nd, a[1] * nd);
  u.h[1] = __floats2half2_rn(a[2] * nd, a[3] * nd);
  u.h[2] = __floats2half2_rn(a[4] * nd, a[5] * nd);
  u.h[3] = __floats2half2_rn(a[6] * nd, a[7] * nd);
  ((float4*)(out + (size_t)node * 128))[lane] = u.f;
}

// ---------------- readout ----------------
__global__ __launch_bounds__(256) void gbounds_k(const int* __restrict__ gid,
                                                 int* __restrict__ gstart) {
  int g = threadIdx.x;  // 0..128
  if (g > N_GRAPHS) return;
  int lo = 0, hi = N_NODES;
  while (lo < hi) {
    int mid = (lo + hi) >> 1;
    if (gid[mid] < g) lo = mid + 1; else hi = mid;
  }
  gstart[g] = lo;
}

__global__ __launch_bounds__(128) void gsum_k(const __half* __restrict__ A16,
                                              const int* __restrict__ gid,
                                              float* gsum) {
  int c = threadIdx.x;
  int n0 = blockIdx.x * 128;
  int n1 = n0 + 128;
  if (n1 > N_NODES) n1 = N_NODES;
  int cur = gid[n0];
  float local = 0.f;
  for (int n = n0; n < n1; ++n) {
    int g = gid[n];  // sorted: few changes per block
    if (g != cur) {
      atomicAdd(&gsum[cur * 128 + c], local);
      local = 0.f;
      cur = g;
    }
    local += __half2float(A16[(size_t)n * 128 + c]);
  }
  atomicAdd(&gsum[cur * 128 + c], local);
}

__global__ __launch_bounds__(128) void gout_k(const float* __restrict__ gsum,
                                              const int* __restrict__ gstart,
                                              float* __restrict__ out) {
  int g = blockIdx.x, c = threadIdx.x;
  float cnt = (float)(gstart[g + 1] - gstart[g]);
  if (cnt < 1.f) cnt = 1.f;
  out[g * 128 + c] = gsum[g * 128 + c] / cnt;
}

// ---------------- launch ----------------
extern "C" void kernel_launch(void* const* d_in, const int* in_sizes, int n_in,
                              void* d_out, int out_size, void* d_ws,
                              size_t ws_size, hipStream_t stream) {
  const float* h = (const float*)d_in[0];
  const int* src = (const int*)d_in[1];
  const int* dst = (const int*)d_in[2];
  const int* gid = (const int*)d_in[3];
  const float* W_embed = (const float*)d_in[4];
  const float* b_embed = (const float*)d_in[5];
  const float* W_layers = (const float*)d_in[6];
  const float* b_layers = (const float*)d_in[7];
  const float* gamma = (const float*)d_in[8];
  const float* beta = (const float*)d_in[9];
  float* out = (float*)d_out;
  (void)in_sizes; (void)n_in; (void)out_size; (void)ws_size;

  char* ws = (char*)d_ws;
  size_t o = 0;
  auto alloc = [&](size_t bytes) -> char* {
    char* p = ws + o;
    o = (o + bytes + 255) & ~(size_t)255;
    return p;
  };
  int* cnt_d = (int*)alloc(NBUCK * 4);  // zeroed (one memset w/ cnt_s)
  int* cnt_s = (int*)alloc(NBUCK * 4);
  int* base_d = (int*)alloc((NBUCK + 1) * 4);
  int* cur_d = (int*)alloc(NBUCK * 4);
  int* base_s = (int*)alloc((NBUCK + 1) * 4);
  int* cur_s = (int*)alloc(NBUCK * 4);
  float* norm_src = (float*)alloc(N_NODES * 4);
  float* norm_dst = (float*)alloc(N_NODES * 4);
  int* deg_out = (int*)alloc(N_NODES * 4);
  int* row_start = (int*)alloc((N_NODES + 1) * 4);
  int* csr_src = (int*)alloc((size_t)N_EDGES * 4);
  int* packed = (int*)alloc((size_t)N_EDGES * 4);
  unsigned short* locs = (unsigned short*)alloc((size_t)N_EDGES * 2);
  float* stats4 = (float*)alloc(N_LAYERS * 256 * 4);  // per-layer sum|sumsq
  float* gsum = (float*)alloc(N_GRAPHS * 128 * 4);    // adjacent to stats4
  int* gstart = (int*)alloc((N_GRAPHS + 1) * 4);
  __half* Bsw = (__half*)alloc(5 * 16384 * 2);
  __half* A16 = (__half*)alloc((size_t)N_NODES * 128 * 2);  // residual (fp16)
  unsigned char* P0f8 = (unsigned char*)alloc((size_t)N_NODES * 128);  // fp8
  __half* P1h = (__half*)alloc((size_t)N_NODES * 128 * 2);  // agg (fp16)
  __half* H16 = (__half*)alloc((size_t)N_NODES * 128 * 2);  // hl (fp16)

  // zero bucket counters and stats (+gsum, contiguous)
  hipMemsetAsync(cnt_d, 0, 2048, stream);
  hipMemsetAsync(stats4, 0, 4096 + 65536, stream);

  // ---- radix CSR build ----
  binA_k<<<256, 256, 0, stream>>>(src, dst, cnt_d, cnt_s);
  scan196_k<<<1, 256, 0, stream>>>(cnt_d, cnt_s, base_d, cur_d, base_s, cur_s,
                                   row_start);
  scat_k<<<256, 256, 0, stream>>>(src, dst, cur_d, cur_s, packed, locs);
  cd_k<<<NBUCK, 256, 0, stream>>>(base_d, packed, row_start, csr_src);
  cs_k<<<NBUCK, 256, 0, stream>>>(base_s, locs, deg_out);
  norm_k<<<(N_NODES + 255) / 256, 256, 0, stream>>>(deg_out, row_start,
                                                    norm_src, norm_dst);

  wswz_k<<<8, 256, 0, stream>>>(W_embed, Bsw);
  wswz_k<<<32, 256, 0, stream>>>(W_layers, Bsw + 16384);

  // embed: A16 = fp16(h @ W_embed + b) ; P0f8 = fp8(. * norm_src)
  mfma_gemm_f32in<<<(N_NODES + 63) / 64, 256, 0, stream>>>(
      h, Bsw, b_embed, A16, P0f8, norm_src);

  for (int l = 0; l < N_LAYERS; ++l) {
    gather_k<<<(N_NODES * 16 + 255) / 256, 256, 0, stream>>>(
        (const uint2*)P0f8, row_start, csr_src, norm_dst, P1h);
    mfma_gemm_f16<<<(N_NODES + 63) / 64, 256, 0, stream>>>(
        P1h, Bsw + (size_t)(1 + l) * 16384, b_layers + l * DIM, H16,
        stats4 + l * 256);
    bnrelu_k<<<(N_NODES * 16 + 255) / 256, 256, 0, stream>>>(
        H16, A16, P0f8, stats4 + l * 256, gamma + l * DIM, beta + l * DIM,
        norm_src, (l < N_LAYERS - 1) ? 1 : 0);
  }

  gbounds_k<<<1, 256, 0, stream>>>(gid, gstart);
  gsum_k<<<(N_NODES + 127) / 128, 128, 0, stream>>>(A16, gid, gsum);
  gout_k<<<N_GRAPHS, 128, 0, stream>>>(gsum, gstart, out);
}

// Round 12
// 575.039 us; speedup vs baseline: 1.6625x; 1.1868x over previous
//
#include <hip/hip_runtime.h>
#include <hip/hip_bf16.h>
#include <hip/hip_fp16.h>

// GCN forward. fp16 inter-layer tensors; gather operand fp8 e4m3 (one
// 128B cache line per row); fp32 accum everywhere.
// R3: MFMA GEMM, pre-swizzled W. R7: radix-bucketed CSR build.
// R8: 64-row GEMM tiles; fp16 residual.
// R10: fp8 gather operand (halves random-read line traffic).
// R11: BN stats 64x-replicated — R10 counters showed mfma_gemm_f16 at 58us
//     with ALL pipes <10%: 1563 co-resident blocks serialized on the same
//     256 stats addresses (device-scope far-atomic chain). Replica = bid&63
//     cuts the chain 64x; bn_fin_k (restored) collapses replicas -> sc_sh.

#define N_NODES 100000
#define N_EDGES 1600000
#define N_GRAPHS 128
#define DIM 128
#define N_LAYERS 4
#define BN_EPS 1e-5f
#define NBUCK 196          // ceil(N_NODES/512)
#define EPB 6250           // edges per block in bin/scatter passes (256 blocks)
#define SREP 64            // stats replicas (atomic-chain 1563 -> ~24)

typedef __attribute__((ext_vector_type(8))) _Float16 half8;
typedef __attribute__((ext_vector_type(4))) float floatx4;
typedef __attribute__((ext_vector_type(2))) float floatx2;

// ---------------- pass A: bucket counts (LDS hist, 196 bins) ----------------
__global__ __launch_bounds__(256) void binA_k(const int* __restrict__ src,
                                              const int* __restrict__ dst,
                                              int* __restrict__ cnt_d,
                                              int* __restrict__ cnt_s) {
  __shared__ int hd[NBUCK], hs[NBUCK];
  int t = threadIdx.x;
  for (int i = t; i < NBUCK; i += 256) { hd[i] = 0; hs[i] = 0; }
  __syncthreads();
  int e0 = blockIdx.x * EPB;
  for (int e = e0 + t; e < e0 + EPB; e += 256) {
    atomicAdd(&hd[dst[e] >> 9], 1);
    atomicAdd(&hs[src[e] >> 9], 1);
  }
  __syncthreads();
  for (int i = t; i < NBUCK; i += 256) {
    if (hd[i]) atomicAdd(&cnt_d[i], hd[i]);
    if (hs[i]) atomicAdd(&cnt_s[i], hs[i]);
  }
}

// ---------------- scan of bucket counts -> bases + cursors ----------------
__global__ __launch_bounds__(256) void scan196_k(
    const int* __restrict__ cnt_d, const int* __restrict__ cnt_s,
    int* __restrict__ base_d, int* __restrict__ cur_d,
    int* __restrict__ base_s, int* __restrict__ cur_s,
    int* __restrict__ row_start) {
  __shared__ int sd[256], ss[256];
  int t = threadIdx.x;
  int vd = (t < NBUCK) ? cnt_d[t] : 0;
  int vs = (t < NBUCK) ? cnt_s[t] : 0;
  sd[t] = vd;
  ss[t] = vs;
  __syncthreads();
  for (int off = 1; off < 256; off <<= 1) {
    int ad = (t >= off) ? sd[t - off] : 0;
    int as = (t >= off) ? ss[t - off] : 0;
    __syncthreads();
    sd[t] += ad;
    ss[t] += as;
    __syncthreads();
  }
  if (t < NBUCK) {
    base_d[t] = sd[t] - vd;
    cur_d[t] = sd[t] - vd;
    base_s[t] = ss[t] - vs;
    cur_s[t] = ss[t] - vs;
  }
  if (t == 0) {
    base_d[NBUCK] = N_EDGES;
    base_s[NBUCK] = N_EDGES;
    row_start[N_NODES] = N_EDGES;
  }
}

// ---------------- pass B: scatter edges into bucket regions ----------------
// packed = (dst&511)<<17 | src  (src < 2^17). locs = src&511 (u16).
__global__ __launch_bounds__(256) void scat_k(
    const int* __restrict__ src, const int* __restrict__ dst,
    int* __restrict__ cur_d, int* __restrict__ cur_s,
    int* __restrict__ packed, unsigned short* __restrict__ locs) {
  __shared__ int hd[NBUCK], hs[NBUCK];
  int t = threadIdx.x;
  for (int i = t; i < NBUCK; i += 256) { hd[i] = 0; hs[i] = 0; }
  __syncthreads();
  int e0 = blockIdx.x * EPB;
  for (int e = e0 + t; e < e0 + EPB; e += 256) {
    atomicAdd(&hd[dst[e] >> 9], 1);
    atomicAdd(&hs[src[e] >> 9], 1);
  }
  __syncthreads();
  if (t < NBUCK) {  // claim chunks; hd/hs become running cursors
    hd[t] = atomicAdd(&cur_d[t], hd[t]);
    hs[t] = atomicAdd(&cur_s[t], hs[t]);
  }
  __syncthreads();
  for (int e = e0 + t; e < e0 + EPB; e += 256) {
    int s = src[e], d = dst[e];
    int slot = atomicAdd(&hd[d >> 9], 1);
    packed[slot] = ((d & 511) << 17) | s;
    int slot2 = atomicAdd(&hs[s >> 9], 1);
    locs[slot2] = (unsigned short)(s & 511);
  }
}

// ---------------- pass C (dst): per-bucket CSR: row_start + csr fill -------
__global__ __launch_bounds__(256) void cd_k(const int* __restrict__ base_d,
                                            const int* __restrict__ packed,
                                            int* __restrict__ row_start,
                                            int* __restrict__ csr_src) {
  __shared__ int sdeg[512], sinc[512], scur[512];
  int t = threadIdx.x;
  int b = blockIdx.x;
  int nbase = b << 9;
  int e0 = base_d[b], e1 = base_d[b + 1];
  sdeg[t] = 0;
  sdeg[t + 256] = 0;
  __syncthreads();
  for (int e = e0 + t; e < e1; e += 256) atomicAdd(&sdeg[packed[e] >> 17], 1);
  __syncthreads();
  sinc[t] = sdeg[t];
  sinc[t + 256] = sdeg[t + 256];
  __syncthreads();
  for (int off = 1; off < 512; off <<= 1) {
    int a0 = (t >= off) ? sinc[t - off] : 0;
    int i1 = t + 256;
    int a1 = (i1 >= off) ? sinc[i1 - off] : 0;
    __syncthreads();
    sinc[t] += a0;
    sinc[i1] += a1;
    __syncthreads();
  }
#pragma unroll
  for (int half = 0; half < 2; ++half) {
    int j = t + half * 256;
    int lofs = e0 + sinc[j] - sdeg[j];
    scur[j] = lofs;
    int node = nbase + j;
    if (node < N_NODES) row_start[node] = lofs;
  }
  __syncthreads();
  for (int e = e0 + t; e < e1; e += 256) {
    int p = packed[e];
    int slot = atomicAdd(&scur[p >> 17], 1);
    csr_src[slot] = p & 0x1FFFF;
  }
}

// ---------------- pass C (src): per-bucket histogram -> deg_out ------------
__global__ __launch_bounds__(256) void cs_k(const int* __restrict__ base_s,
                                            const unsigned short* __restrict__ locs,
                                            int* __restrict__ deg_out) {
  __shared__ int sdeg[512];
  int t = threadIdx.x;
  int b = blockIdx.x;
  int nbase = b << 9;
  int e0 = base_s[b], e1 = base_s[b + 1];
  sdeg[t] = 0;
  sdeg[t + 256] = 0;
  __syncthreads();
  for (int e = e0 + t; e < e1; e += 256) atomicAdd(&sdeg[locs[e]], 1);
  __syncthreads();
#pragma unroll
  for (int half = 0; half < 2; ++half) {
    int j = t + half * 256;
    int node = nbase + j;
    if (node < N_NODES) deg_out[node] = sdeg[j];
  }
}

// ---------------- norms (deg_in = row_start diff) ----------------
__global__ __launch_bounds__(256) void norm_k(const int* __restrict__ deg_out,
                                              const int* __restrict__ row_start,
                                              float* __restrict__ norm_src,
                                              float* __restrict__ norm_dst) {
  int i = blockIdx.x * 256 + threadIdx.x;
  if (i < N_NODES) {
    int din = row_start[i + 1] - row_start[i];
    int dso = deg_out[i] > 1 ? deg_out[i] : 1;
    int dsi = din > 1 ? din : 1;
    norm_src[i] = rsqrtf((float)dso);
    norm_dst[i] = rsqrtf((float)dsi);
  }
}

// ---------------- W pre-swizzle to B-fragment layout ----------------
__global__ __launch_bounds__(256) void wswz_k(const float* __restrict__ W,
                                              __half* __restrict__ Bsw) {
  int w = blockIdx.x >> 3, ct = blockIdx.x & 7;
  int ks = threadIdx.x >> 6, lane = threadIdx.x & 63;
  int n = ct * 16 + (lane & 15);
  int k0 = ks * 32 + (lane >> 4) * 8;
  const float* Wm = W + (size_t)w * 16384;
  __half* o = Bsw + ((((size_t)w * 8 + ct) * 4 + ks) * 64 + lane) * 8;
#pragma unroll
  for (int j = 0; j < 8; ++j) o[j] = __float2half(Wm[(k0 + j) * 128 + n]);
}

// ---------------- MFMA core: wave w computes 16 rows x 128 cols ----------
// C layout per 16x16 tile: row = quad*4 + reg, col = ct*16 + lrow.
__device__ inline void mfma_core16(const __half* sA,
                                   const __half* __restrict__ Bsw,
                                   floatx4 (&acc)[8], int w, int lane,
                                   int quad, int lrow) {
#pragma unroll
  for (int ct = 0; ct < 8; ++ct) acc[ct] = (floatx4)(0.f);
#pragma unroll
  for (int ks = 0; ks < 4; ++ks) {
    int m = w * 16 + lrow;
    half8 afrag = *(const half8*)(&sA[m * 136 + ks * 32 + quad * 8]);
#pragma unroll
    for (int ct = 0; ct < 8; ++ct) {
      half8 bfrag = *(const half8*)(&Bsw[(((size_t)ct * 4 + ks) * 64 + lane) * 8]);
      acc[ct] = __builtin_amdgcn_mfma_f32_16x16x32_f16(afrag, bfrag, acc[ct],
                                                       0, 0, 0);
    }
  }
}

// ---------------- embed GEMM: A16 = fp16(h @ W + b); P0f8 = fp8(.*ns) ------
__global__ __launch_bounds__(256) void mfma_gemm_f32in(
    const float* __restrict__ X32, const __half* __restrict__ Bsw,
    const float* __restrict__ bias, __half* __restrict__ A16,
    unsigned char* __restrict__ S8, const float* __restrict__ norm_src) {
  __shared__ __half sA[64 * 136];  // 17.4 KB
  const int tid = threadIdx.x;
  const int w = tid >> 6, lane = tid & 63;
  const int quad = lane >> 4, lrow = lane & 15;
  const int row_base = blockIdx.x * 64;

  // stage fp32 tile -> fp16 LDS (2048 float4 reads)
#pragma unroll
  for (int i = 0; i < 8; ++i) {
    int g = i * 256 + tid;
    int r = g >> 5, q = g & 31;
    int row = row_base + r;
    float4 v = make_float4(0.f, 0.f, 0.f, 0.f);
    if (row < N_NODES) v = ((const float4*)X32)[(size_t)row * 32 + q];
    union { __half2 h[2]; float f[2]; } u;
    u.h[0] = __floats2half2_rn(v.x, v.y);
    u.h[1] = __floats2half2_rn(v.z, v.w);
    *(float2*)(&sA[r * 136 + q * 4]) = *(float2*)u.f;
  }
  __syncthreads();

  floatx4 acc[8];
  mfma_core16(sA, Bsw, acc, w, lane, quad, lrow);

#pragma unroll
  for (int ct = 0; ct < 8; ++ct) {
    int col = ct * 16 + lrow;
    float b = bias[col];
#pragma unroll
    for (int reg = 0; reg < 4; ++reg) {
      int row = row_base + w * 16 + quad * 4 + reg;
      if (row < N_NODES) {
        float y = acc[ct][reg] + b;
        A16[(size_t)row * 128 + col] = __float2half(y);
        unsigned pb =
            __builtin_amdgcn_cvt_pk_fp8_f32(y * norm_src[row], 0.f, 0, false);
        S8[(size_t)row * 128 + col] = (unsigned char)(pb & 0xFF);
      }
    }
  }
}

// ---------------- layer GEMM: hl16 = fp16(agg16 @ W + b), + BN stats ------
// stats replicated SREP x: block b adds into replica (b & SREP-1).
__global__ __launch_bounds__(256) void mfma_gemm_f16(
    const __half* __restrict__ X16, const __half* __restrict__ Bsw,
    const float* __restrict__ bias, __half* __restrict__ hl16,
    float* __restrict__ stats) {
  __shared__ __half sA[64 * 136];
  const int tid = threadIdx.x;
  const int w = tid >> 6, lane = tid & 63;
  const int quad = lane >> 4, lrow = lane & 15;
  const int row_base = blockIdx.x * 64;

  // stage fp16 tile (1024 float4 reads)
#pragma unroll
  for (int i = 0; i < 4; ++i) {
    int g = i * 256 + tid;
    int r = g >> 4, p = g & 15;
    int row = row_base + r;
    float4 v = make_float4(0.f, 0.f, 0.f, 0.f);
    if (row < N_NODES) v = ((const float4*)X16)[(size_t)row * 16 + p];
    *(float4*)(&sA[r * 136 + p * 8]) = v;
  }
  __syncthreads();

  floatx4 acc[8];
  mfma_core16(sA, Bsw, acc, w, lane, quad, lrow);

  float psum[8], pqsum[8];
#pragma unroll
  for (int ct = 0; ct < 8; ++ct) {
    int col = ct * 16 + lrow;
    float b = bias[col];
    psum[ct] = 0.f;
    pqsum[ct] = 0.f;
#pragma unroll
    for (int reg = 0; reg < 4; ++reg) {
      int row = row_base + w * 16 + quad * 4 + reg;
      if (row < N_NODES) {
        float y = acc[ct][reg] + b;
        hl16[(size_t)row * 128 + col] = __float2half(y);
        psum[ct] += y;
        pqsum[ct] += y * y;
      }
    }
  }

#pragma unroll
  for (int ct = 0; ct < 8; ++ct) {
    psum[ct] += __shfl_xor(psum[ct], 16, 64);
    psum[ct] += __shfl_xor(psum[ct], 32, 64);
    pqsum[ct] += __shfl_xor(pqsum[ct], 16, 64);
    pqsum[ct] += __shfl_xor(pqsum[ct], 32, 64);
  }
  __syncthreads();
  float* sred = (float*)sA;  // [4 waves][128] sum | [4][128] sumsq
  if (quad == 0) {
#pragma unroll
    for (int ct = 0; ct < 8; ++ct) {
      sred[w * 128 + ct * 16 + lrow] = psum[ct];
      sred[512 + w * 128 + ct * 16 + lrow] = pqsum[ct];
    }
  }
  __syncthreads();
  if (tid < 128) {
    float s = sred[tid] + sred[128 + tid] + sred[256 + tid] + sred[384 + tid];
    float q = sred[512 + tid] + sred[640 + tid] + sred[768 + tid] +
              sred[896 + tid];
    float* st = stats + (size_t)(blockIdx.x & (SREP - 1)) * 256;
    atomicAdd(&st[tid], s);
    atomicAdd(&st[128 + tid], q);
  }
}

// ---------------- BN finalize: collapse SREP replicas -> sc_sh ----------
__global__ __launch_bounds__(128) void bn_fin_k(const float* __restrict__ stats,
                                                const float* __restrict__ gamma,
                                                const float* __restrict__ beta,
                                                float* __restrict__ sc_sh) {
  int c = threadIdx.x;
  float s = 0.f, q = 0.f;
  for (int r = 0; r < SREP; ++r) {
    s += stats[r * 256 + c];
    q += stats[r * 256 + 128 + c];
  }
  const float invn = 1.0f / (float)N_NODES;
  float mean = s * invn;
  float var = q * invn - mean * mean;
  var = fmaxf(var, 0.f);
  float sc = gamma[c] * rsqrtf(var + BN_EPS);
  sc_sh[c] = sc;
  sc_sh[128 + c] = beta[c] - mean * sc;
}

// ---------------- BN apply + ReLU + residual ----------------
// Writes fp8 scaled copy (gather operand) when write_scaled.
__global__ __launch_bounds__(256) void bnrelu_k(
    const __half* __restrict__ hl16, __half* __restrict__ A16,
    unsigned char* __restrict__ S8, const float* __restrict__ sc_sh,
    const float* __restrict__ norm_src, int write_scaled) {
  int idx = blockIdx.x * 256 + threadIdx.x;  // < N_NODES*16
  int node = idx >> 4;
  int c8 = idx & 15;
  float4 hv4 = *(const float4*)(hl16 + (size_t)idx * 8);
  float4 av4 = *(const float4*)(A16 + (size_t)idx * 8);
  const __half2* hp = (const __half2*)&hv4;
  const __half2* ap = (const __half2*)&av4;
  const float4* sv = (const float4*)sc_sh;
  float4 s0 = sv[c8 * 2], s1 = sv[c8 * 2 + 1];
  float4 b0 = sv[32 + c8 * 2], b1 = sv[32 + c8 * 2 + 1];
  float n = write_scaled ? norm_src[node] : 0.f;
  float2 f0 = __half22float2(hp[0]), f1 = __half22float2(hp[1]);
  float2 f2 = __half22float2(hp[2]), f3 = __half22float2(hp[3]);
  float2 a0 = __half22float2(ap[0]), a1 = __half22float2(ap[1]);
  float2 a2 = __half22float2(ap[2]), a3 = __half22float2(ap[3]);
  float v[8];
  v[0] = fmaxf(f0.x * s0.x + b0.x, 0.f) + a0.x;
  v[1] = fmaxf(f0.y * s0.y + b0.y, 0.f) + a0.y;
  v[2] = fmaxf(f1.x * s0.z + b0.z, 0.f) + a1.x;
  v[3] = fmaxf(f1.y * s0.w + b0.w, 0.f) + a1.y;
  v[4] = fmaxf(f2.x * s1.x + b1.x, 0.f) + a2.x;
  v[5] = fmaxf(f2.y * s1.y + b1.y, 0.f) + a2.y;
  v[6] = fmaxf(f3.x * s1.z + b1.z, 0.f) + a3.x;
  v[7] = fmaxf(f3.y * s1.w + b1.w, 0.f) + a3.y;
  union { __half2 h[4]; float4 f; } ua;
#pragma unroll
  for (int q = 0; q < 4; ++q)
    ua.h[q] = __floats2half2_rn(v[2 * q], v[2 * q + 1]);
  *(float4*)(A16 + (size_t)idx * 8) = ua.f;
  if (write_scaled) {
    unsigned lo = 0, hi = 0;
    lo = __builtin_amdgcn_cvt_pk_fp8_f32(v[0] * n, v[1] * n, lo, false);
    lo = __builtin_amdgcn_cvt_pk_fp8_f32(v[2] * n, v[3] * n, lo, true);
    hi = __builtin_amdgcn_cvt_pk_fp8_f32(v[4] * n, v[5] * n, hi, false);
    hi = __builtin_amdgcn_cvt_pk_fp8_f32(v[6] * n, v[7] * n, hi, true);
    ((uint2*)S8)[idx] = make_uint2(lo, hi);
  }
}

// ---------------- pull aggregation (fp8 in, fp16 out, fp32 accum) ---------
// 16 lanes/node, lane owns 8 fp8 cols (8B); one 128B line per edge.
__device__ inline void accf8(float (&a)[8], uint2 v) {
  floatx2 f;
  f = __builtin_amdgcn_cvt_pk_f32_fp8(v.x, false); a[0] += f.x; a[1] += f.y;
  f = __builtin_amdgcn_cvt_pk_f32_fp8(v.x, true);  a[2] += f.x; a[3] += f.y;
  f = __builtin_amdgcn_cvt_pk_f32_fp8(v.y, false); a[4] += f.x; a[5] += f.y;
  f = __builtin_amdgcn_cvt_pk_f32_fp8(v.y, true);  a[6] += f.x; a[7] += f.y;
}

__global__ __launch_bounds__(256) void gather_k(
    const uint2* __restrict__ Hs, const int* __restrict__ row_start,
    const int* __restrict__ csr_src, const float* __restrict__ norm_dst,
    __half* __restrict__ out) {
  int node = (blockIdx.x * 256 + threadIdx.x) >> 4;
  int lane = threadIdx.x & 15;
  if (node >= N_NODES) return;
  int s0 = row_start[node], s1 = row_start[node + 1];
  float a[8] = {0.f, 0.f, 0.f, 0.f, 0.f, 0.f, 0.f, 0.f};
  for (int e = s0; e < s1; e += 16) {
    int cnt = s1 - e;
    if (cnt > 16) cnt = 16;
    int idx = (lane < cnt) ? csr_src[e + lane] : 0;
    int j = 0;
    for (; j + 8 <= cnt; j += 8) {
      uint2 v0 = Hs[(size_t)__shfl(idx, j, 16) * 16 + lane];
      uint2 v1 = Hs[(size_t)__shfl(idx, j + 1, 16) * 16 + lane];
      uint2 v2 = Hs[(size_t)__shfl(idx, j + 2, 16) * 16 + lane];
      uint2 v3 = Hs[(size_t)__shfl(idx, j + 3, 16) * 16 + lane];
      uint2 v4 = Hs[(size_t)__shfl(idx, j + 4, 16) * 16 + lane];
      uint2 v5 = Hs[(size_t)__shfl(idx, j + 5, 16) * 16 + lane];
      uint2 v6 = Hs[(size_t)__shfl(idx, j + 6, 16) * 16 + lane];
      uint2 v7 = Hs[(size_t)__shfl(idx, j + 7, 16) * 16 + lane];
      accf8(a, v0); accf8(a, v1); accf8(a, v2); accf8(a, v3);
      accf8(a, v4); accf8(a, v5); accf8(a, v6); accf8(a, v7);
    }
    for (; j + 4 <= cnt; j += 4) {
      uint2 v0 = Hs[(size_t)__shfl(idx, j, 16) * 16 + lane];
      uint2 v1 = Hs[(size_t)__shfl(idx, j + 1, 16) * 16 + lane];
      uint2 v2 = Hs[(size_t)__shfl(idx, j + 2, 16) * 16 + lane];
      uint2 v3 = Hs[(size_t)__shfl(idx, j + 3, 16) * 16 + lane];
      accf8(a, v0); accf8(a, v1); accf8(a, v2); accf8(a, v3);
    }
    for (; j < cnt; ++j) {
      accf8(a, Hs[(size_t)__shfl(idx, j, 16) * 16 + lane]);
    }
  }
  float nd = norm_dst[node];
  union { __half2 h[4]; float4 f; } u;
  u.h[0] = __floats2half2_rn(a[0] * nd, a[1] * nd);
  u.h[1] = __floats2half2_rn(a[2] * nd, a[3] * nd);
  u.h[2] = __floats2half2_rn(a[4] * nd, a[5] * nd);
  u.h[3] = __floats2half2_rn(a[6] * nd, a[7] * nd);
  ((float4*)(out + (size_t)node * 128))[lane] = u.f;
}

// ---------------- readout ----------------
__global__ __launch_bounds__(256) void gbounds_k(const int* __restrict__ gid,
                                                 int* __restrict__ gstart) {
  int g = threadIdx.x;  // 0..128
  if (g > N_GRAPHS) return;
  int lo = 0, hi = N_NODES;
  while (lo < hi) {
    int mid = (lo + hi) >> 1;
    if (gid[mid] < g) lo = mid + 1; else hi = mid;
  }
  gstart[g] = lo;
}

__global__ __launch_bounds__(128) void gsum_k(const __half* __restrict__ A16,
                                              const int* __restrict__ gid,
                                              float* gsum) {
  int c = threadIdx.x;
  int n0 = blockIdx.x * 128;
  int n1 = n0 + 128;
  if (n1 > N_NODES) n1 = N_NODES;
  int cur = gid[n0];
  float local = 0.f;
  for (int n = n0; n < n1; ++n) {
    int g = gid[n];  // sorted: few changes per block
    if (g != cur) {
      atomicAdd(&gsum[cur * 128 + c], local);
      local = 0.f;
      cur = g;
    }
    local += __half2float(A16[(size_t)n * 128 + c]);
  }
  atomicAdd(&gsum[cur * 128 + c], local);
}

__global__ __launch_bounds__(128) void gout_k(const float* __restrict__ gsum,
                                              const int* __restrict__ gstart,
                                              float* __restrict__ out) {
  int g = blockIdx.x, c = threadIdx.x;
  float cnt = (float)(gstart[g + 1] - gstart[g]);
  if (cnt < 1.f) cnt = 1.f;
  out[g * 128 + c] = gsum[g * 128 + c] / cnt;
}

// ---------------- launch ----------------
extern "C" void kernel_launch(void* const* d_in, const int* in_sizes, int n_in,
                              void* d_out, int out_size, void* d_ws,
                              size_t ws_size, hipStream_t stream) {
  const float* h = (const float*)d_in[0];
  const int* src = (const int*)d_in[1];
  const int* dst = (const int*)d_in[2];
  const int* gid = (const int*)d_in[3];
  const float* W_embed = (const float*)d_in[4];
  const float* b_embed = (const float*)d_in[5];
  const float* W_layers = (const float*)d_in[6];
  const float* b_layers = (const float*)d_in[7];
  const float* gamma = (const float*)d_in[8];
  const float* beta = (const float*)d_in[9];
  float* out = (float*)d_out;
  (void)in_sizes; (void)n_in; (void)out_size; (void)ws_size;

  char* ws = (char*)d_ws;
  size_t o = 0;
  auto alloc = [&](size_t bytes) -> char* {
    char* p = ws + o;
    o = (o + bytes + 255) & ~(size_t)255;
    return p;
  };
  int* cnt_d = (int*)alloc(NBUCK * 4);  // zeroed (one memset w/ cnt_s)
  int* cnt_s = (int*)alloc(NBUCK * 4);
  int* base_d = (int*)alloc((NBUCK + 1) * 4);
  int* cur_d = (int*)alloc(NBUCK * 4);
  int* base_s = (int*)alloc((NBUCK + 1) * 4);
  int* cur_s = (int*)alloc(NBUCK * 4);
  float* norm_src = (float*)alloc(N_NODES * 4);
  float* norm_dst = (float*)alloc(N_NODES * 4);
  int* deg_out = (int*)alloc(N_NODES * 4);
  int* row_start = (int*)alloc((N_NODES + 1) * 4);
  int* csr_src = (int*)alloc((size_t)N_EDGES * 4);
  int* packed = (int*)alloc((size_t)N_EDGES * 4);
  unsigned short* locs = (unsigned short*)alloc((size_t)N_EDGES * 2);
  float* stats = (float*)alloc((size_t)SREP * 256 * 4);  // replicated
  float* gsum = (float*)alloc(N_GRAPHS * 128 * 4);       // adjacent to stats
  int* gstart = (int*)alloc((N_GRAPHS + 1) * 4);
  float* sc_sh = (float*)alloc(256 * 4);
  __half* Bsw = (__half*)alloc(5 * 16384 * 2);
  __half* A16 = (__half*)alloc((size_t)N_NODES * 128 * 2);  // residual (fp16)
  unsigned char* P0f8 = (unsigned char*)alloc((size_t)N_NODES * 128);  // fp8
  __half* P1h = (__half*)alloc((size_t)N_NODES * 128 * 2);  // agg (fp16)
  __half* H16 = (__half*)alloc((size_t)N_NODES * 128 * 2);  // hl (fp16)

  // zero bucket counters; zero stats replicas + gsum (contiguous)
  hipMemsetAsync(cnt_d, 0, 2048, stream);
  hipMemsetAsync(stats, 0, SREP * 256 * 4 + 65536, stream);

  // ---- radix CSR build ----
  binA_k<<<256, 256, 0, stream>>>(src, dst, cnt_d, cnt_s);
  scan196_k<<<1, 256, 0, stream>>>(cnt_d, cnt_s, base_d, cur_d, base_s, cur_s,
                                   row_start);
  scat_k<<<256, 256, 0, stream>>>(src, dst, cur_d, cur_s, packed, locs);
  cd_k<<<NBUCK, 256, 0, stream>>>(base_d, packed, row_start, csr_src);
  cs_k<<<NBUCK, 256, 0, stream>>>(base_s, locs, deg_out);
  norm_k<<<(N_NODES + 255) / 256, 256, 0, stream>>>(deg_out, row_start,
                                                    norm_src, norm_dst);

  wswz_k<<<8, 256, 0, stream>>>(W_embed, Bsw);
  wswz_k<<<32, 256, 0, stream>>>(W_layers, Bsw + 16384);

  // embed: A16 = fp16(h @ W_embed + b) ; P0f8 = fp8(. * norm_src)
  mfma_gemm_f32in<<<(N_NODES + 63) / 64, 256, 0, stream>>>(
      h, Bsw, b_embed, A16, P0f8, norm_src);

  for (int l = 0; l < N_LAYERS; ++l) {
    if (l) hipMemsetAsync(stats, 0, SREP * 256 * 4, stream);
    gather_k<<<(N_NODES * 16 + 255) / 256, 256, 0, stream>>>(
        (const uint2*)P0f8, row_start, csr_src, norm_dst, P1h);
    mfma_gemm_f16<<<(N_NODES + 63) / 64, 256, 0, stream>>>(
        P1h, Bsw + (size_t)(1 + l) * 16384, b_layers + l * DIM, H16, stats);
    bn_fin_k<<<1, 128, 0, stream>>>(stats, gamma + l * DIM, beta + l * DIM,
                                    sc_sh);
    bnrelu_k<<<(N_NODES * 16 + 255) / 256, 256, 0, stream>>>(
        H16, A16, P0f8, sc_sh, norm_src, (l < N_LAYERS - 1) ? 1 : 0);
  }

  gbounds_k<<<1, 256, 0, stream>>>(gid, gstart);
  gsum_k<<<(N_NODES + 127) / 128, 128, 0, stream>>>(A16, gid, gsum);
  gout_k<<<N_GRAPHS, 128, 0, stream>>>(gsum, gstart, out);
}

// Round 13
// 571.622 us; speedup vs baseline: 1.6724x; 1.0060x over previous
//
#include <hip/hip_runtime.h>
#include <hip/hip_bf16.h>
#include <hip/hip_fp16.h>

// GCN forward. fp16 inter-layer tensors; gather operand fp8 e4m3 (one
// 128B cache line per row); fp32 accum everywhere.
// R3: MFMA GEMM, pre-swizzled W. R7: radix-bucketed CSR build.
// R8: 64-row GEMM tiles; fp16 residual. R10: fp8 gather operand.
// R11: BN stats 64x-replicated (kills 1563-deep far-atomic chain).
// R12: gather 8 lanes/node with uint4 loads (1 wave-instr per 128B line,
//     half the load+shfl count, bit-identical accumulation order);
//     binA_k persists per-block histograms so scat_k skips its re-histogram
//     pass; norm folded into cd_k/cs_k; single wswz launch; per-layer stats
//     buffers with one upfront memset (-6 dispatches).

#define N_NODES 100000
#define N_EDGES 1600000
#define N_GRAPHS 128
#define DIM 128
#define N_LAYERS 4
#define BN_EPS 1e-5f
#define NBUCK 196          // ceil(N_NODES/512)
#define EPB 6250           // edges per block in bin/scatter passes (256 blocks)
#define SREP 64            // stats replicas (atomic-chain 1563 -> ~24)

typedef __attribute__((ext_vector_type(8))) _Float16 half8;
typedef __attribute__((ext_vector_type(4))) float floatx4;
typedef __attribute__((ext_vector_type(2))) float floatx2;

// ---------------- pass A: bucket counts + per-block histograms ----------------
__global__ __launch_bounds__(256) void binA_k(const int* __restrict__ src,
                                              const int* __restrict__ dst,
                                              int* __restrict__ cnt_d,
                                              int* __restrict__ cnt_s,
                                              int* __restrict__ bh_d,
                                              int* __restrict__ bh_s) {
  __shared__ int hd[NBUCK], hs[NBUCK];
  int t = threadIdx.x;
  for (int i = t; i < NBUCK; i += 256) { hd[i] = 0; hs[i] = 0; }
  __syncthreads();
  int e0 = blockIdx.x * EPB;
  for (int e = e0 + t; e < e0 + EPB; e += 256) {
    atomicAdd(&hd[dst[e] >> 9], 1);
    atomicAdd(&hs[src[e] >> 9], 1);
  }
  __syncthreads();
  for (int i = t; i < NBUCK; i += 256) {
    int v = hd[i], v2 = hs[i];
    bh_d[blockIdx.x * NBUCK + i] = v;
    bh_s[blockIdx.x * NBUCK + i] = v2;
    if (v) atomicAdd(&cnt_d[i], v);
    if (v2) atomicAdd(&cnt_s[i], v2);
  }
}

// ---------------- scan of bucket counts -> bases + cursors ----------------
__global__ __launch_bounds__(256) void scan196_k(
    const int* __restrict__ cnt_d, const int* __restrict__ cnt_s,
    int* __restrict__ base_d, int* __restrict__ cur_d,
    int* __restrict__ base_s, int* __restrict__ cur_s,
    int* __restrict__ row_start) {
  __shared__ int sd[256], ss[256];
  int t = threadIdx.x;
  int vd = (t < NBUCK) ? cnt_d[t] : 0;
  int vs = (t < NBUCK) ? cnt_s[t] : 0;
  sd[t] = vd;
  ss[t] = vs;
  __syncthreads();
  for (int off = 1; off < 256; off <<= 1) {
    int ad = (t >= off) ? sd[t - off] : 0;
    int as = (t >= off) ? ss[t - off] : 0;
    __syncthreads();
    sd[t] += ad;
    ss[t] += as;
    __syncthreads();
  }
  if (t < NBUCK) {
    base_d[t] = sd[t] - vd;
    cur_d[t] = sd[t] - vd;
    base_s[t] = ss[t] - vs;
    cur_s[t] = ss[t] - vs;
  }
  if (t == 0) {
    base_d[NBUCK] = N_EDGES;
    base_s[NBUCK] = N_EDGES;
    row_start[N_NODES] = N_EDGES;
  }
}

// ---------------- pass B: scatter edges into bucket regions ----------------
// Uses binA's per-block histograms (no re-histogram pass).
// packed = (dst&511)<<17 | src  (src < 2^17). locs = src&511 (u16).
__global__ __launch_bounds__(256) void scat_k(
    const int* __restrict__ src, const int* __restrict__ dst,
    int* __restrict__ cur_d, int* __restrict__ cur_s,
    const int* __restrict__ bh_d, const int* __restrict__ bh_s,
    int* __restrict__ packed, unsigned short* __restrict__ locs) {
  __shared__ int hd[NBUCK], hs[NBUCK];
  int t = threadIdx.x;
  for (int i = t; i < NBUCK; i += 256) {
    hd[i] = bh_d[blockIdx.x * NBUCK + i];
    hs[i] = bh_s[blockIdx.x * NBUCK + i];
  }
  __syncthreads();
  if (t < NBUCK) {  // claim chunks; hd/hs become running cursors
    hd[t] = atomicAdd(&cur_d[t], hd[t]);
    hs[t] = atomicAdd(&cur_s[t], hs[t]);
  }
  __syncthreads();
  int e0 = blockIdx.x * EPB;
  for (int e = e0 + t; e < e0 + EPB; e += 256) {
    int s = src[e], d = dst[e];
    int slot = atomicAdd(&hd[d >> 9], 1);
    packed[slot] = ((d & 511) << 17) | s;
    int slot2 = atomicAdd(&hs[s >> 9], 1);
    locs[slot2] = (unsigned short)(s & 511);
  }
}

// ---------------- pass C (dst): row_start + csr fill + norm_dst -----------
__global__ __launch_bounds__(256) void cd_k(const int* __restrict__ base_d,
                                            const int* __restrict__ packed,
                                            int* __restrict__ row_start,
                                            int* __restrict__ csr_src,
                                            float* __restrict__ norm_dst) {
  __shared__ int sdeg[512], sinc[512], scur[512];
  int t = threadIdx.x;
  int b = blockIdx.x;
  int nbase = b << 9;
  int e0 = base_d[b], e1 = base_d[b + 1];
  sdeg[t] = 0;
  sdeg[t + 256] = 0;
  __syncthreads();
  for (int e = e0 + t; e < e1; e += 256) atomicAdd(&sdeg[packed[e] >> 17], 1);
  __syncthreads();
  sinc[t] = sdeg[t];
  sinc[t + 256] = sdeg[t + 256];
  __syncthreads();
  for (int off = 1; off < 512; off <<= 1) {
    int a0 = (t >= off) ? sinc[t - off] : 0;
    int i1 = t + 256;
    int a1 = (i1 >= off) ? sinc[i1 - off] : 0;
    __syncthreads();
    sinc[t] += a0;
    sinc[i1] += a1;
    __syncthreads();
  }
#pragma unroll
  for (int half = 0; half < 2; ++half) {
    int j = t + half * 256;
    int lofs = e0 + sinc[j] - sdeg[j];
    scur[j] = lofs;
    int node = nbase + j;
    if (node < N_NODES) {
      row_start[node] = lofs;
      int d = sdeg[j];
      norm_dst[node] = rsqrtf((float)(d > 1 ? d : 1));
    }
  }
  __syncthreads();
  for (int e = e0 + t; e < e1; e += 256) {
    int p = packed[e];
    int slot = atomicAdd(&scur[p >> 17], 1);
    csr_src[slot] = p & 0x1FFFF;
  }
}

// ---------------- pass C (src): per-bucket histogram -> norm_src ----------
__global__ __launch_bounds__(256) void cs_k(const int* __restrict__ base_s,
                                            const unsigned short* __restrict__ locs,
                                            float* __restrict__ norm_src) {
  __shared__ int sdeg[512];
  int t = threadIdx.x;
  int b = blockIdx.x;
  int nbase = b << 9;
  int e0 = base_s[b], e1 = base_s[b + 1];
  sdeg[t] = 0;
  sdeg[t + 256] = 0;
  __syncthreads();
  for (int e = e0 + t; e < e1; e += 256) atomicAdd(&sdeg[locs[e]], 1);
  __syncthreads();
#pragma unroll
  for (int half = 0; half < 2; ++half) {
    int j = t + half * 256;
    int node = nbase + j;
    if (node < N_NODES) {
      int d = sdeg[j];
      norm_src[node] = rsqrtf((float)(d > 1 ? d : 1));
    }
  }
}

// ---------------- W pre-swizzle (all 5 matrices, one launch) ----------------
__global__ __launch_bounds__(256) void wswz_k(const float* __restrict__ W_embed,
                                              const float* __restrict__ W_layers,
                                              __half* __restrict__ Bsw) {
  int m = blockIdx.x >> 3, ct = blockIdx.x & 7;  // m: 0=embed, 1..4=layers
  const float* Wm =
      (m == 0) ? W_embed : (W_layers + (size_t)(m - 1) * 16384);
  int ks = threadIdx.x >> 6, lane = threadIdx.x & 63;
  int n = ct * 16 + (lane & 15);
  int k0 = ks * 32 + (lane >> 4) * 8;
  __half* o = Bsw + ((((size_t)m * 8 + ct) * 4 + ks) * 64 + lane) * 8;
#pragma unroll
  for (int j = 0; j < 8; ++j) o[j] = __float2half(Wm[(k0 + j) * 128 + n]);
}

// ---------------- MFMA core: wave w computes 16 rows x 128 cols ----------
// C layout per 16x16 tile: row = quad*4 + reg, col = ct*16 + lrow.
__device__ inline void mfma_core16(const __half* sA,
                                   const __half* __restrict__ Bsw,
                                   floatx4 (&acc)[8], int w, int lane,
                                   int quad, int lrow) {
#pragma unroll
  for (int ct = 0; ct < 8; ++ct) acc[ct] = (floatx4)(0.f);
#pragma unroll
  for (int ks = 0; ks < 4; ++ks) {
    int m = w * 16 + lrow;
    half8 afrag = *(const half8*)(&sA[m * 136 + ks * 32 + quad * 8]);
#pragma unroll
    for (int ct = 0; ct < 8; ++ct) {
      half8 bfrag = *(const half8*)(&Bsw[(((size_t)ct * 4 + ks) * 64 + lane) * 8]);
      acc[ct] = __builtin_amdgcn_mfma_f32_16x16x32_f16(afrag, bfrag, acc[ct],
                                                       0, 0, 0);
    }
  }
}

// ---------------- embed GEMM: A16 = fp16(h @ W + b); P0f8 = fp8(.*ns) ------
__global__ __launch_bounds__(256) void mfma_gemm_f32in(
    const float* __restrict__ X32, const __half* __restrict__ Bsw,
    const float* __restrict__ bias, __half* __restrict__ A16,
    unsigned char* __restrict__ S8, const float* __restrict__ norm_src) {
  __shared__ __half sA[64 * 136];  // 17.4 KB
  const int tid = threadIdx.x;
  const int w = tid >> 6, lane = tid & 63;
  const int quad = lane >> 4, lrow = lane & 15;
  const int row_base = blockIdx.x * 64;

  // stage fp32 tile -> fp16 LDS (2048 float4 reads)
#pragma unroll
  for (int i = 0; i < 8; ++i) {
    int g = i * 256 + tid;
    int r = g >> 5, q = g & 31;
    int row = row_base + r;
    float4 v = make_float4(0.f, 0.f, 0.f, 0.f);
    if (row < N_NODES) v = ((const float4*)X32)[(size_t)row * 32 + q];
    union { __half2 h[2]; float f[2]; } u;
    u.h[0] = __floats2half2_rn(v.x, v.y);
    u.h[1] = __floats2half2_rn(v.z, v.w);
    *(float2*)(&sA[r * 136 + q * 4]) = *(float2*)u.f;
  }
  __syncthreads();

  floatx4 acc[8];
  mfma_core16(sA, Bsw, acc, w, lane, quad, lrow);

#pragma unroll
  for (int ct = 0; ct < 8; ++ct) {
    int col = ct * 16 + lrow;
    float b = bias[col];
#pragma unroll
    for (int reg = 0; reg < 4; ++reg) {
      int row = row_base + w * 16 + quad * 4 + reg;
      if (row < N_NODES) {
        float y = acc[ct][reg] + b;
        A16[(size_t)row * 128 + col] = __float2half(y);
        unsigned pb =
            __builtin_amdgcn_cvt_pk_fp8_f32(y * norm_src[row], 0.f, 0, false);
        S8[(size_t)row * 128 + col] = (unsigned char)(pb & 0xFF);
      }
    }
  }
}

// ---------------- layer GEMM: hl16 = fp16(agg16 @ W + b), + BN stats ------
// stats replicated SREP x: block b adds into replica (b & SREP-1).
__global__ __launch_bounds__(256) void mfma_gemm_f16(
    const __half* __restrict__ X16, const __half* __restrict__ Bsw,
    const float* __restrict__ bias, __half* __restrict__ hl16,
    float* __restrict__ stats) {
  __shared__ __half sA[64 * 136];
  const int tid = threadIdx.x;
  const int w = tid >> 6, lane = tid & 63;
  const int quad = lane >> 4, lrow = lane & 15;
  const int row_base = blockIdx.x * 64;

  // stage fp16 tile (1024 float4 reads)
#pragma unroll
  for (int i = 0; i < 4; ++i) {
    int g = i * 256 + tid;
    int r = g >> 4, p = g & 15;
    int row = row_base + r;
    float4 v = make_float4(0.f, 0.f, 0.f, 0.f);
    if (row < N_NODES) v = ((const float4*)X16)[(size_t)row * 16 + p];
    *(float4*)(&sA[r * 136 + p * 8]) = v;
  }
  __syncthreads();

  floatx4 acc[8];
  mfma_core16(sA, Bsw, acc, w, lane, quad, lrow);

  float psum[8], pqsum[8];
#pragma unroll
  for (int ct = 0; ct < 8; ++ct) {
    int col = ct * 16 + lrow;
    float b = bias[col];
    psum[ct] = 0.f;
    pqsum[ct] = 0.f;
#pragma unroll
    for (int reg = 0; reg < 4; ++reg) {
      int row = row_base + w * 16 + quad * 4 + reg;
      if (row < N_NODES) {
        float y = acc[ct][reg] + b;
        hl16[(size_t)row * 128 + col] = __float2half(y);
        psum[ct] += y;
        pqsum[ct] += y * y;
      }
    }
  }

#pragma unroll
  for (int ct = 0; ct < 8; ++ct) {
    psum[ct] += __shfl_xor(psum[ct], 16, 64);
    psum[ct] += __shfl_xor(psum[ct], 32, 64);
    pqsum[ct] += __shfl_xor(pqsum[ct], 16, 64);
    pqsum[ct] += __shfl_xor(pqsum[ct], 32, 64);
  }
  __syncthreads();
  float* sred = (float*)sA;  // [4 waves][128] sum | [4][128] sumsq
  if (quad == 0) {
#pragma unroll
    for (int ct = 0; ct < 8; ++ct) {
      sred[w * 128 + ct * 16 + lrow] = psum[ct];
      sred[512 + w * 128 + ct * 16 + lrow] = pqsum[ct];
    }
  }
  __syncthreads();
  if (tid < 128) {
    float s = sred[tid] + sred[128 + tid] + sred[256 + tid] + sred[384 + tid];
    float q = sred[512 + tid] + sred[640 + tid] + sred[768 + tid] +
              sred[896 + tid];
    float* st = stats + (size_t)(blockIdx.x & (SREP - 1)) * 256;
    atomicAdd(&st[tid], s);
    atomicAdd(&st[128 + tid], q);
  }
}

// ---------------- BN finalize: collapse SREP replicas -> sc_sh ----------
__global__ __launch_bounds__(128) void bn_fin_k(const float* __restrict__ stats,
                                                const float* __restrict__ gamma,
                                                const float* __restrict__ beta,
                                                float* __restrict__ sc_sh) {
  int c = threadIdx.x;
  float s = 0.f, q = 0.f;
  for (int r = 0; r < SREP; ++r) {
    s += stats[r * 256 + c];
    q += stats[r * 256 + 128 + c];
  }
  const float invn = 1.0f / (float)N_NODES;
  float mean = s * invn;
  float var = q * invn - mean * mean;
  var = fmaxf(var, 0.f);
  float sc = gamma[c] * rsqrtf(var + BN_EPS);
  sc_sh[c] = sc;
  sc_sh[128 + c] = beta[c] - mean * sc;
}

// ---------------- BN apply + ReLU + residual ----------------
__global__ __launch_bounds__(256) void bnrelu_k(
    const __half* __restrict__ hl16, __half* __restrict__ A16,
    unsigned char* __restrict__ S8, const float* __restrict__ sc_sh,
    const float* __restrict__ norm_src, int write_scaled) {
  int idx = blockIdx.x * 256 + threadIdx.x;  // < N_NODES*16
  int node = idx >> 4;
  int c8 = idx & 15;
  float4 hv4 = *(const float4*)(hl16 + (size_t)idx * 8);
  float4 av4 = *(const float4*)(A16 + (size_t)idx * 8);
  const __half2* hp = (const __half2*)&hv4;
  const __half2* ap = (const __half2*)&av4;
  const float4* sv = (const float4*)sc_sh;
  float4 s0 = sv[c8 * 2], s1 = sv[c8 * 2 + 1];
  float4 b0 = sv[32 + c8 * 2], b1 = sv[32 + c8 * 2 + 1];
  float n = write_scaled ? norm_src[node] : 0.f;
  float2 f0 = __half22float2(hp[0]), f1 = __half22float2(hp[1]);
  float2 f2 = __half22float2(hp[2]), f3 = __half22float2(hp[3]);
  float2 a0 = __half22float2(ap[0]), a1 = __half22float2(ap[1]);
  float2 a2 = __half22float2(ap[2]), a3 = __half22float2(ap[3]);
  float v[8];
  v[0] = fmaxf(f0.x * s0.x + b0.x, 0.f) + a0.x;
  v[1] = fmaxf(f0.y * s0.y + b0.y, 0.f) + a0.y;
  v[2] = fmaxf(f1.x * s0.z + b0.z, 0.f) + a1.x;
  v[3] = fmaxf(f1.y * s0.w + b0.w, 0.f) + a1.y;
  v[4] = fmaxf(f2.x * s1.x + b1.x, 0.f) + a2.x;
  v[5] = fmaxf(f2.y * s1.y + b1.y, 0.f) + a2.y;
  v[6] = fmaxf(f3.x * s1.z + b1.z, 0.f) + a3.x;
  v[7] = fmaxf(f3.y * s1.w + b1.w, 0.f) + a3.y;
  union { __half2 h[4]; float4 f; } ua;
#pragma unroll
  for (int q = 0; q < 4; ++q)
    ua.h[q] = __floats2half2_rn(v[2 * q], v[2 * q + 1]);
  *(float4*)(A16 + (size_t)idx * 8) = ua.f;
  if (write_scaled) {
    unsigned lo = 0, hi = 0;
    lo = __builtin_amdgcn_cvt_pk_fp8_f32(v[0] * n, v[1] * n, lo, false);
    lo = __builtin_amdgcn_cvt_pk_fp8_f32(v[2] * n, v[3] * n, lo, true);
    hi = __builtin_amdgcn_cvt_pk_fp8_f32(v[4] * n, v[5] * n, hi, false);
    hi = __builtin_amdgcn_cvt_pk_fp8_f32(v[6] * n, v[7] * n, hi, true);
    ((uint2*)S8)[idx] = make_uint2(lo, hi);
  }
}

// ---------------- pull aggregation (fp8 in, fp16 out, fp32 accum) ---------
// 8 lanes/node, lane owns 16 fp8 cols (one uint4 = 16B); a wave covers a
// full 128B line in ONE load instruction. Per-column accumulation order
// identical to the 16-lane version (same edge j sequence) -> bit-exact.
__device__ inline void accf8x16(float (&a)[16], uint4 v) {
  floatx2 f;
  f = __builtin_amdgcn_cvt_pk_f32_fp8(v.x, false); a[0] += f.x;  a[1] += f.y;
  f = __builtin_amdgcn_cvt_pk_f32_fp8(v.x, true);  a[2] += f.x;  a[3] += f.y;
  f = __builtin_amdgcn_cvt_pk_f32_fp8(v.y, false); a[4] += f.x;  a[5] += f.y;
  f = __builtin_amdgcn_cvt_pk_f32_fp8(v.y, true);  a[6] += f.x;  a[7] += f.y;
  f = __builtin_amdgcn_cvt_pk_f32_fp8(v.z, false); a[8] += f.x;  a[9] += f.y;
  f = __builtin_amdgcn_cvt_pk_f32_fp8(v.z, true);  a[10] += f.x; a[11] += f.y;
  f = __builtin_amdgcn_cvt_pk_f32_fp8(v.w, false); a[12] += f.x; a[13] += f.y;
  f = __builtin_amdgcn_cvt_pk_f32_fp8(v.w, true);  a[14] += f.x; a[15] += f.y;
}

__global__ __launch_bounds__(256) void gather_k(
    const uint4* __restrict__ Hs, const int* __restrict__ row_start,
    const int* __restrict__ csr_src, const float* __restrict__ norm_dst,
    __half* __restrict__ out) {
  int node = (blockIdx.x * 256 + threadIdx.x) >> 3;
  int lane = threadIdx.x & 7;
  if (node >= N_NODES) return;
  int s0 = row_start[node], s1 = row_start[node + 1];
  float a[16];
#pragma unroll
  for (int i = 0; i < 16; ++i) a[i] = 0.f;
  for (int e = s0; e < s1; e += 8) {
    int cnt = s1 - e;
    if (cnt > 8) cnt = 8;
    int idx = (lane < cnt) ? csr_src[e + lane] : 0;
    int j = 0;
    for (; j + 4 <= cnt; j += 4) {
      uint4 v0 = Hs[(size_t)__shfl(idx, j, 8) * 8 + lane];
      uint4 v1 = Hs[(size_t)__shfl(idx, j + 1, 8) * 8 + lane];
      uint4 v2 = Hs[(size_t)__shfl(idx, j + 2, 8) * 8 + lane];
      uint4 v3 = Hs[(size_t)__shfl(idx, j + 3, 8) * 8 + lane];
      accf8x16(a, v0); accf8x16(a, v1); accf8x16(a, v2); accf8x16(a, v3);
    }
    for (; j < cnt; ++j) {
      accf8x16(a, Hs[(size_t)__shfl(idx, j, 8) * 8 + lane]);
    }
  }
  float nd = norm_dst[node];
  union { __half2 h[8]; float4 f[2]; } u;
#pragma unroll
  for (int q = 0; q < 8; ++q)
    u.h[q] = __floats2half2_rn(a[2 * q] * nd, a[2 * q + 1] * nd);
  float4* op = (float4*)(out + (size_t)node * 128 + lane * 16);
  op[0] = u.f[0];
  op[1] = u.f[1];
}

// ---------------- readout ----------------
__global__ __launch_bounds__(256) void gbounds_k(const int* __restrict__ gid,
                                                 int* __restrict__ gstart) {
  int g = threadIdx.x;  // 0..128
  if (g > N_GRAPHS) return;
  int lo = 0, hi = N_NODES;
  while (lo < hi) {
    int mid = (lo + hi) >> 1;
    if (gid[mid] < g) lo = mid + 1; else hi = mid;
  }
  gstart[g] = lo;
}

__global__ __launch_bounds__(128) void gsum_k(const __half* __restrict__ A16,
                                              const int* __restrict__ gid,
                                              float* gsum) {
  int c = threadIdx.x;
  int n0 = blockIdx.x * 128;
  int n1 = n0 + 128;
  if (n1 > N_NODES) n1 = N_NODES;
  int cur = gid[n0];
  float local = 0.f;
  for (int n = n0; n < n1; ++n) {
    int g = gid[n];  // sorted: few changes per block
    if (g != cur) {
      atomicAdd(&gsum[cur * 128 + c], local);
      local = 0.f;
      cur = g;
    }
    local += __half2float(A16[(size_t)n * 128 + c]);
  }
  atomicAdd(&gsum[cur * 128 + c], local);
}

__global__ __launch_bounds__(128) void gout_k(const float* __restrict__ gsum,
                                              const int* __restrict__ gstart,
                                              float* __restrict__ out) {
  int g = blockIdx.x, c = threadIdx.x;
  float cnt = (float)(gstart[g + 1] - gstart[g]);
  if (cnt < 1.f) cnt = 1.f;
  out[g * 128 + c] = gsum[g * 128 + c] / cnt;
}

// ---------------- launch ----------------
extern "C" void kernel_launch(void* const* d_in, const int* in_sizes, int n_in,
                              void* d_out, int out_size, void* d_ws,
                              size_t ws_size, hipStream_t stream) {
  const float* h = (const float*)d_in[0];
  const int* src = (const int*)d_in[1];
  const int* dst = (const int*)d_in[2];
  const int* gid = (const int*)d_in[3];
  const float* W_embed = (const float*)d_in[4];
  const float* b_embed = (const float*)d_in[5];
  const float* W_layers = (const float*)d_in[6];
  const float* b_layers = (const float*)d_in[7];
  const float* gamma = (const float*)d_in[8];
  const float* beta = (const float*)d_in[9];
  float* out = (float*)d_out;
  (void)in_sizes; (void)n_in; (void)out_size; (void)ws_size;

  char* ws = (char*)d_ws;
  size_t o = 0;
  auto alloc = [&](size_t bytes) -> char* {
    char* p = ws + o;
    o = (o + bytes + 255) & ~(size_t)255;
    return p;
  };
  int* cnt_d = (int*)alloc(NBUCK * 4);  // zeroed (one memset w/ cnt_s)
  int* cnt_s = (int*)alloc(NBUCK * 4);
  int* base_d = (int*)alloc((NBUCK + 1) * 4);
  int* cur_d = (int*)alloc(NBUCK * 4);
  int* base_s = (int*)alloc((NBUCK + 1) * 4);
  int* cur_s = (int*)alloc(NBUCK * 4);
  int* bh_d = (int*)alloc((size_t)256 * NBUCK * 4);
  int* bh_s = (int*)alloc((size_t)256 * NBUCK * 4);
  float* norm_src = (float*)alloc(N_NODES * 4);
  float* norm_dst = (float*)alloc(N_NODES * 4);
  int* row_start = (int*)alloc((N_NODES + 1) * 4);
  int* csr_src = (int*)alloc((size_t)N_EDGES * 4);
  int* packed = (int*)alloc((size_t)N_EDGES * 4);
  unsigned short* locs = (unsigned short*)alloc((size_t)N_EDGES * 2);
  float* stats4 = (float*)alloc((size_t)N_LAYERS * SREP * 256 * 4);
  float* gsum = (float*)alloc(N_GRAPHS * 128 * 4);  // adjacent to stats4
  int* gstart = (int*)alloc((N_GRAPHS + 1) * 4);
  float* sc_sh = (float*)alloc(256 * 4);
  __half* Bsw = (__half*)alloc(5 * 16384 * 2);
  __half* A16 = (__half*)alloc((size_t)N_NODES * 128 * 2);  // residual (fp16)
  unsigned char* P0f8 = (unsigned char*)alloc((size_t)N_NODES * 128);  // fp8
  __half* P1h = (__half*)alloc((size_t)N_NODES * 128 * 2);  // agg (fp16)
  __half* H16 = (__half*)alloc((size_t)N_NODES * 128 * 2);  // hl (fp16)

  // zero bucket counters; zero all per-layer stats replicas + gsum
  hipMemsetAsync(cnt_d, 0, 2048, stream);
  hipMemsetAsync(stats4, 0, (size_t)N_LAYERS * SREP * 256 * 4 + 65536, stream);

  // ---- radix CSR build ----
  binA_k<<<256, 256, 0, stream>>>(src, dst, cnt_d, cnt_s, bh_d, bh_s);
  scan196_k<<<1, 256, 0, stream>>>(cnt_d, cnt_s, base_d, cur_d, base_s, cur_s,
                                   row_start);
  scat_k<<<256, 256, 0, stream>>>(src, dst, cur_d, cur_s, bh_d, bh_s, packed,
                                  locs);
  cd_k<<<NBUCK, 256, 0, stream>>>(base_d, packed, row_start, csr_src,
                                  norm_dst);
  cs_k<<<NBUCK, 256, 0, stream>>>(base_s, locs, norm_src);

  wswz_k<<<40, 256, 0, stream>>>(W_embed, W_layers, Bsw);

  // embed: A16 = fp16(h @ W_embed + b) ; P0f8 = fp8(. * norm_src)
  mfma_gemm_f32in<<<(N_NODES + 63) / 64, 256, 0, stream>>>(
      h, Bsw, b_embed, A16, P0f8, norm_src);

  for (int l = 0; l < N_LAYERS; ++l) {
    float* stats = stats4 + (size_t)l * SREP * 256;
    gather_k<<<(N_NODES * 8 + 255) / 256, 256, 0, stream>>>(
        (const uint4*)P0f8, row_start, csr_src, norm_dst, P1h);
    mfma_gemm_f16<<<(N_NODES + 63) / 64, 256, 0, stream>>>(
        P1h, Bsw + (size_t)(1 + l) * 16384, b_layers + l * DIM, H16, stats);
    bn_fin_k<<<1, 128, 0, stream>>>(stats, gamma + l * DIM, beta + l * DIM,
                                    sc_sh);
    bnrelu_k<<<(N_NODES * 16 + 255) / 256, 256, 0, stream>>>(
        H16, A16, P0f8, sc_sh, norm_src, (l < N_LAYERS - 1) ? 1 : 0);
  }

  gbounds_k<<<1, 256, 0, stream>>>(gid, gstart);
  gsum_k<<<(N_NODES + 127) / 128, 128, 0, stream>>>(A16, gid, gsum);
  gout_k<<<N_GRAPHS, 128, 0, stream>>>(gsum, gstart, out);
}